// Round 2
// baseline (6068.142 us; speedup 1.0000x reference)
//
#include <hip/hip_runtime.h>

#define Bk 8
#define Nk 2048
#define Ck 16
#define Dk 64
#define Tk 32
#define MAXD 256
#define GBLK 256

typedef __attribute__((ext_vector_type(8))) short short8;
typedef __attribute__((ext_vector_type(4))) float floatx4;

// ---------- LDS layout (dynamic, one block/CU) ----------
#define OFF_WCAT 0           // [256][136] bf16  vertex gate weights (Wih_left|Whh)
#define OFF_VW1  69632       // [112][72]  bf16  vmsg W1 (padded 100->112)
#define OFF_VW2  85760       // [64][136]  bf16  vmsg W2 (K padded 100->128, zeros)
#define OFF_AT   103168      // [64][136]  bf16  A-tile (gather|vh_prev), reused
#define OFF_HT   120576      // [64][136]  bf16  hidden tile (cols 112..135 stay zero)
#define OFF_CH   137984      // [16][64] f32 ch (block-local color state)
#define OFF_CC   142080      // [16][64] f32 cc
#define OFF_GC   146176      // [256] f32 gate const (cm term + biases)
#define OFF_VBS  147200      // [256] f32 v_bih+v_bhh
#define OFF_CBS  148224      // [256] f32 c_bih+c_bhh
#define OFF_VB1  149248      // [112] f32
#define OFF_VB2  149760      // [64]  f32
#define OFF_CB1  150016      // [112] f32
#define OFF_CB2  150528      // [64]  f32
#define OFF_W1V  150784      // [16][64] f32 vote W1
#define OFF_B1V  154880      // [16] f32
#define OFF_W2V  154944      // [16] f32
#define OFF_VAC  155008      // [64] f32 vmsg accum (LDS atomics)
#define OFF_VMS  155264      // [64] f32 vmsg_sum (batch)
#define OFF_CMS  155520      // [64] f32 cm_sum
#define OFF_VOT  155776      // [256] f32 vote scratch
#define LDS_TOTAL 156800

__device__ __forceinline__ float b2f(unsigned short u) {
  return __uint_as_float(((unsigned)u) << 16);
}
__device__ __forceinline__ unsigned short f2b(float f) {
  unsigned u = __float_as_uint(f);
  unsigned r = (u + 0x7FFFu + ((u >> 16) & 1u)) >> 16;
  return (unsigned short)r;
}
__device__ __forceinline__ float sigf(float x) { return 1.0f / (1.0f + __expf(-x)); }
__device__ __forceinline__ float tanhf_(float x) { return 2.0f / (1.0f + __expf(-2.0f * x)) - 1.0f; }

// ---------- one-time init kernels ----------
__global__ void k_init_w(const float* vWih, const float* vWhh, const float* cWih, const float* cWhh,
                         const float* vm1, const float* vm2, const float* cm1, const float* cm2,
                         unsigned short* wcat, unsigned short* cwcat,
                         unsigned short* vw1, unsigned short* vw2,
                         unsigned short* cw1, unsigned short* cw2,
                         unsigned* bar, float* voteAcc) {
  const int tid = threadIdx.x;
  for (int i = tid; i < 256 * 128; i += 256) {
    int g = i >> 7, k = i & 127;
    wcat[i]  = f2b(k < 64 ? vWih[g * 128 + k] : vWhh[g * 64 + (k - 64)]);
    cwcat[i] = f2b(k < 64 ? cWih[g * 64 + k]  : cWhh[g * 64 + (k - 64)]);
  }
  for (int i = tid; i < 112 * 64; i += 256) {
    int j = i >> 6, k = i & 63;
    vw1[i] = f2b(j < 100 ? vm1[j * 64 + k] : 0.f);
    cw1[i] = f2b(j < 100 ? cm1[j * 64 + k] : 0.f);
  }
  for (int i = tid; i < 64 * 128; i += 256) {
    int d = i >> 7, k = i & 127;
    vw2[i] = f2b(k < 100 ? vm2[d * 100 + k] : 0.f);
    cw2[i] = f2b(k < 100 ? cm2[d * 100 + k] : 0.f);
  }
  if (tid == 0) *bar = 0u;
  if (tid < 8) voteAcc[tid] = 0.f;
}

__global__ void k_init_vh(const float* vInit, unsigned short* vh0) {
  for (int i = blockIdx.x * blockDim.x + threadIdx.x; i < Bk * Nk * Dk; i += gridDim.x * blockDim.x)
    vh0[i] = f2b(vInit[i & 63]);
}

// build per-row neighbor lists from dense 0/1 Mvv (one wave per row)
__global__ void k_build(const float* Mvv, unsigned short* nbrIdx, int* nbrCnt) {
  const int lane = threadIdx.x & 63;
  const int wid = blockIdx.x * 4 + (threadIdx.x >> 6);   // global row id in [0, B*N)
  const float* row = Mvv + (size_t)wid * Nk;
  unsigned short* lst = nbrIdx + (size_t)wid * MAXD;
  int cnt = 0;
  for (int c0 = 0; c0 < Nk; c0 += 64) {
    float v = row[c0 + lane];
    unsigned long long m = __ballot(v != 0.0f);
    if (v != 0.0f) {
      int pos = cnt + __popcll(m & ((1ull << lane) - 1ull));
      if (pos < MAXD) lst[pos] = (unsigned short)(c0 + lane);
    }
    cnt += __popcll(m);
  }
  if (lane == 0) nbrCnt[wid] = cnt > MAXD ? MAXD : cnt;
}

// ---------- persistent kernel ----------
struct PArgs {
  const float *vWih, *chInit;
  const float *vbih, *vbhh, *cbih, *cbhh;
  const float *vmb1, *vmb2, *cmb1, *cmb2;
  const float *voW1, *vob1, *voW2, *vob2;
  const int* ncolors;
  unsigned short* vhbuf;         // [2][B][N][D] bf16
  const int* nbrCnt;
  const unsigned short* nbrIdx;
  float* partial;                // [2][GBLK][64]
  const unsigned short *wcat, *cwcat, *vw1, *vw2, *cw1, *cw2;
  unsigned* bar;
  float* voteAcc;
  float* out;
};

__device__ __forceinline__ void gridbar(unsigned* bar, unsigned target) {
  __syncthreads();
  if (threadIdx.x == 0) {
    __threadfence();   // agent-scope release
    atomicAdd(bar, 1u);
    int guard = 0;
    while (__hip_atomic_load(bar, __ATOMIC_RELAXED, __HIP_MEMORY_SCOPE_AGENT) < target) {
      __builtin_amdgcn_s_sleep(2);
      if (++guard > (1 << 24)) break;   // bail instead of wedging the GPU
    }
  }
  __syncthreads();
  __threadfence();     // agent-scope acquire
}

__global__ void __launch_bounds__(256, 1) k_persist(PArgs A) {
  extern __shared__ char smem[];
  unsigned short* WcatU  = (unsigned short*)(smem + OFF_WCAT);
  unsigned short* vW1U   = (unsigned short*)(smem + OFF_VW1);
  unsigned short* vW2U   = (unsigned short*)(smem + OFF_VW2);
  unsigned short* AtileU = (unsigned short*)(smem + OFF_AT);
  unsigned short* HtileU = (unsigned short*)(smem + OFF_HT);
  float* chl = (float*)(smem + OFF_CH);
  float* ccl = (float*)(smem + OFF_CC);
  float* gc  = (float*)(smem + OFF_GC);
  float* vbs = (float*)(smem + OFF_VBS);
  float* cbs = (float*)(smem + OFF_CBS);
  float* vb1 = (float*)(smem + OFF_VB1);
  float* vb2 = (float*)(smem + OFF_VB2);
  float* cb1 = (float*)(smem + OFF_CB1);
  float* cb2 = (float*)(smem + OFF_CB2);
  float* W1v = (float*)(smem + OFF_W1V);
  float* b1v = (float*)(smem + OFF_B1V);
  float* W2v = (float*)(smem + OFF_W2V);
  float* vac = (float*)(smem + OFF_VAC);
  float* vms = (float*)(smem + OFF_VMS);
  float* cms = (float*)(smem + OFF_CMS);
  float* vot = (float*)(smem + OFF_VOT);

  const int tid = threadIdx.x;
  const int lane = tid & 63;
  const int w = tid >> 6;          // wave id 0..3 == M-tile
  const int q = lane >> 4;         // quad
  const int l15 = lane & 15;
  const int bb = blockIdx.x & 7;             // batch (XCD-affine)
  const int rb = (blockIdx.x >> 3) * 64;     // row base within batch
  const int ncolv = A.ncolors[bb];
  const floatx4 zf = {0.f, 0.f, 0.f, 0.f};

  // ---- stage weights/biases/state into LDS (once) ----
  for (int i = tid; i < 256 * 128; i += 256) { int g = i >> 7, k = i & 127; WcatU[g * 136 + k] = A.wcat[i]; }
  for (int i = tid; i < 112 * 64; i += 256)  { int j = i >> 6, k = i & 63;  vW1U[j * 72 + k]  = A.vw1[i]; }
  for (int i = tid; i < 64 * 128; i += 256)  { int d = i >> 7, k = i & 127; vW2U[d * 136 + k] = A.vw2[i]; }
  for (int i = tid; i < 64 * 136; i += 256)  HtileU[i] = 0;
  if (tid < 112) { vb1[tid] = (tid < 100) ? A.vmb1[tid] : 0.f; cb1[tid] = (tid < 100) ? A.cmb1[tid] : 0.f; }
  if (tid < 64)  { vb2[tid] = A.vmb2[tid]; cb2[tid] = A.cmb2[tid]; vac[tid] = 0.f; }
  vbs[tid] = A.vbih[tid] + A.vbhh[tid];
  cbs[tid] = A.cbih[tid] + A.cbhh[tid];
  for (int i = tid; i < 1024; i += 256) { W1v[i] = A.voW1[i]; chl[i] = A.chInit[bb * 1024 + i]; ccl[i] = 0.f; }
  if (tid < 16) { b1v[tid] = A.vob1[tid]; W2v[tid] = A.voW2[tid]; }
  __syncthreads();

  // c_msg MLP (on current chl) + cm_sum + vertex-gate-const. Redundant per block.
  auto cmsgPhase = [&]() {
    for (int i = tid; i < 1024; i += 256) { int c = i >> 6, kk = i & 63; AtileU[c * 136 + kk] = f2b(chl[i]); }
    __syncthreads();
    floatx4 m1a = zf, m1b = zf;
#pragma unroll
    for (int ks = 0; ks < 2; ++ks) {
      short8 af = *(const short8*)(AtileU + l15 * 136 + ks * 32 + q * 8);
      short8 b0 = *(const short8*)(A.cw1 + (size_t)((w * 16 + l15) * 64 + ks * 32 + q * 8));
      m1a = __builtin_amdgcn_mfma_f32_16x16x32_bf16(af, b0, m1a, 0, 0, 0);
      if (w < 3) {
        short8 b1 = *(const short8*)(A.cw1 + (size_t)(((w + 4) * 16 + l15) * 64 + ks * 32 + q * 8));
        m1b = __builtin_amdgcn_mfma_f32_16x16x32_bf16(af, b1, m1b, 0, 0, 0);
      }
    }
#pragma unroll
    for (int reg = 0; reg < 4; ++reg) {
      float hv = m1a[reg] + cb1[w * 16 + l15];
      HtileU[(q * 4 + reg) * 136 + w * 16 + l15] = f2b(hv > 0.f ? hv : 0.f);
    }
    if (w < 3) {
#pragma unroll
      for (int reg = 0; reg < 4; ++reg) {
        float hv = m1b[reg] + cb1[(w + 4) * 16 + l15];
        HtileU[(q * 4 + reg) * 136 + (w + 4) * 16 + l15] = f2b(hv > 0.f ? hv : 0.f);
      }
    }
    __syncthreads();
    floatx4 m2 = zf;
#pragma unroll
    for (int ks = 0; ks < 4; ++ks) {
      short8 af = *(const short8*)(HtileU + l15 * 136 + ks * 32 + q * 8);
      short8 bv = *(const short8*)(A.cw2 + (size_t)((w * 16 + l15) * 128 + ks * 32 + q * 8));
      m2 = __builtin_amdgcn_mfma_f32_16x16x32_bf16(af, bv, m2, 0, 0, 0);
    }
    float s2 = 0.f;
#pragma unroll
    for (int reg = 0; reg < 4; ++reg) {
      int c = q * 4 + reg;
      float v = m2[reg] + cb2[w * 16 + l15];
      v = v > 0.f ? v : 0.f;
      if (c < ncolv) s2 += v;
    }
    s2 += __shfl_xor(s2, 16);
    s2 += __shfl_xor(s2, 32);
    if (q == 0) cms[w * 16 + l15] = s2;
    __syncthreads();
    {
      float dot = 0.f;
      const float* wr = A.vWih + tid * 128 + 64;    // right half of v_Wih (cm_sum input)
      for (int k2 = 0; k2 < 64; ++k2) dot += cms[k2] * wr[k2];
      gc[tid] = dot + vbs[tid];
    }
    __syncthreads();
  };

  float vc[4][4] = {};      // vertex cell state, fp32, resident in regs
  cmsgPhase();              // prologue: gate const from ch_init
  unsigned ep = 0;

  for (int t = 0; t < Tk; ++t) {
    const unsigned short* vold = A.vhbuf + (size_t)(t & 1) * (Bk * Nk * Dk) + (size_t)bb * (Nk * Dk);
    unsigned short* vnew = A.vhbuf + (size_t)((t & 1) ^ 1) * (Bk * Nk * Dk) + (size_t)bb * (Nk * Dk);

    // ---- a1: sparse gather A@vh (lane = d), write A-tile [row][0..63]=Avh, [64..127]=vh_prev
    for (int r = 0; r < 16; ++r) {
      const int lrow = w * 16 + r;
      const int grow = rb + lrow;
      const int cnt = A.nbrCnt[bb * Nk + grow];
      const unsigned short* lst = A.nbrIdx + (size_t)(bb * Nk + grow) * MAXD;
      const unsigned short sv = vold[(size_t)grow * 64 + lane];
      float a0 = b2f(sv), a1 = 0.f;
      for (int c0 = 0; c0 < cnt; c0 += 64) {
        const int iv = (int)lst[c0 + lane];
        const int mm = (cnt - c0) < 64 ? (cnt - c0) : 64;
        int k = 0;
#pragma unroll 4
        for (; k + 1 < mm; k += 2) {
          int j0 = __builtin_amdgcn_readlane(iv, k);
          int j1 = __builtin_amdgcn_readlane(iv, k + 1);
          a0 += b2f(vold[(size_t)j0 * 64 + lane]);
          a1 += b2f(vold[(size_t)j1 * 64 + lane]);
        }
        if (k < mm) {
          int j0 = __builtin_amdgcn_readlane(iv, k);
          a0 += b2f(vold[(size_t)j0 * 64 + lane]);
        }
      }
      AtileU[lrow * 136 + lane] = f2b(a0 + a1);
      AtileU[lrow * 136 + 64 + lane] = sv;
    }

    // ---- a2: gates = [Avh|vh] @ Wcat^T  (M=16 rows of this wave, N=256, K=128)
    floatx4 acc[16];
#pragma unroll
    for (int nt = 0; nt < 16; ++nt) acc[nt] = zf;
#pragma unroll
    for (int ks = 0; ks < 4; ++ks) {
      short8 af = *(const short8*)(AtileU + (w * 16 + l15) * 136 + ks * 32 + q * 8);
#pragma unroll
      for (int nt = 0; nt < 16; ++nt) {
        short8 bv = *(const short8*)(WcatU + (nt * 16 + l15) * 136 + ks * 32 + q * 8);
        acc[nt] = __builtin_amdgcn_mfma_f32_16x16x32_bf16(af, bv, acc[nt], 0, 0, 0);
      }
    }

    // ---- a3/a4: LSTM pointwise; h -> A-tile cols 0..63 (bf16)
#pragma unroll
    for (int u = 0; u < 4; ++u) {
      const int d2 = u * 16 + l15;
      const float gi = gc[d2], gf2 = gc[64 + d2], gg = gc[128 + d2], go = gc[192 + d2];
#pragma unroll
      for (int reg = 0; reg < 4; ++reg) {
        float iv = acc[u][reg] + gi;
        float fv = acc[u + 4][reg] + gf2;
        float gv = acc[u + 8][reg] + gg;
        float ov = acc[u + 12][reg] + go;
        float cn = sigf(fv) * vc[u][reg] + sigf(iv) * tanhf_(gv);
        vc[u][reg] = cn;
        AtileU[(w * 16 + q * 4 + reg) * 136 + d2] = f2b(sigf(ov) * tanhf_(cn));
      }
    }

    // ---- a5: v_msg hidden = relu(h @ W1^T + b1)
    floatx4 h1[7];
#pragma unroll
    for (int nt = 0; nt < 7; ++nt) h1[nt] = zf;
#pragma unroll
    for (int ks = 0; ks < 2; ++ks) {
      short8 af = *(const short8*)(AtileU + (w * 16 + l15) * 136 + ks * 32 + q * 8);
#pragma unroll
      for (int nt = 0; nt < 7; ++nt) {
        short8 bv = *(const short8*)(vW1U + (nt * 16 + l15) * 72 + ks * 32 + q * 8);
        h1[nt] = __builtin_amdgcn_mfma_f32_16x16x32_bf16(af, bv, h1[nt], 0, 0, 0);
      }
    }
#pragma unroll
    for (int nt = 0; nt < 7; ++nt) {
      float bb1 = vb1[nt * 16 + l15];
#pragma unroll
      for (int reg = 0; reg < 4; ++reg) {
        float hv = h1[nt][reg] + bb1;
        HtileU[(w * 16 + q * 4 + reg) * 136 + nt * 16 + l15] = f2b(hv > 0.f ? hv : 0.f);
      }
    }

    // ---- a6: v_msg = relu(hidden @ W2^T + b2); a7: reduce over rows
    floatx4 vm[4];
#pragma unroll
    for (int nt = 0; nt < 4; ++nt) vm[nt] = zf;
#pragma unroll
    for (int ks = 0; ks < 4; ++ks) {
      short8 af = *(const short8*)(HtileU + (w * 16 + l15) * 136 + ks * 32 + q * 8);
#pragma unroll
      for (int nt = 0; nt < 4; ++nt) {
        short8 bv = *(const short8*)(vW2U + (nt * 16 + l15) * 136 + ks * 32 + q * 8);
        vm[nt] = __builtin_amdgcn_mfma_f32_16x16x32_bf16(af, bv, vm[nt], 0, 0, 0);
      }
    }
#pragma unroll
    for (int u = 0; u < 4; ++u) {
      float bb2 = vb2[u * 16 + l15];
      float s = 0.f;
#pragma unroll
      for (int reg = 0; reg < 4; ++reg) { float v = vm[u][reg] + bb2; s += (v > 0.f ? v : 0.f); }
      s += __shfl_xor(s, 16);
      s += __shfl_xor(s, 32);
      if (q == 0) atomicAdd(&vac[u * 16 + l15], s);
    }
    __syncthreads();

    // ---- a9: publish block partial + vh_new (from A-tile, coalesced)
    if (tid < 64) A.partial[(size_t)((t & 1) * GBLK + blockIdx.x) * 64 + tid] = vac[tid];
    for (int i = tid; i < 1024; i += 256) {
      int r = i >> 4, c4 = (i & 15) * 4;
      unsigned long long val = *(const unsigned long long*)(AtileU + r * 136 + c4);
      *(unsigned long long*)(vnew + (size_t)(rb + r) * 64 + c4) = val;
    }
    __syncthreads();
    if (tid < 64) vac[tid] = 0.f;

    gridbar(A.bar, (++ep) * GBLK);

    if (t < Tk - 1) {
      // ---- color phase (redundant per block, local ch/cc) ----
      if (tid < 64) {
        float s = 0.f;
        const float* pp = A.partial + (size_t)((t & 1) * GBLK) * 64;
        for (int i2 = 0; i2 < 32; ++i2) s += pp[(i2 * 8 + bb) * 64 + tid];
        vms[tid] = s;
      }
      __syncthreads();
      for (int i2 = tid; i2 < 16 * 128; i2 += 256) {
        int c = i2 >> 7, kk = i2 & 127;
        float v = (kk < 64) ? ((c < ncolv) ? vms[kk] : 0.f) : chl[c * 64 + (kk - 64)];
        AtileU[c * 136 + kk] = f2b(v);
      }
      __syncthreads();
      floatx4 cacc[4];
#pragma unroll
      for (int j = 0; j < 4; ++j) cacc[j] = zf;
#pragma unroll
      for (int ks = 0; ks < 4; ++ks) {
        short8 af = *(const short8*)(AtileU + l15 * 136 + ks * 32 + q * 8);
#pragma unroll
        for (int j = 0; j < 4; ++j) {
          short8 bv = *(const short8*)(A.cwcat + (size_t)(((w * 4 + j) * 16 + l15) * 128 + ks * 32 + q * 8));
          cacc[j] = __builtin_amdgcn_mfma_f32_16x16x32_bf16(af, bv, cacc[j], 0, 0, 0);
        }
      }
      __syncthreads();
      float* cgp = (float*)(smem + OFF_AT);   // fp32 overlay for gate exchange
#pragma unroll
      for (int j = 0; j < 4; ++j)
#pragma unroll
        for (int reg = 0; reg < 4; ++reg)
          cgp[(q * 4 + reg) * 260 + (w * 4 + j) * 16 + l15] = cacc[j][reg];
      __syncthreads();
      for (int i2 = tid; i2 < 1024; i2 += 256) {
        int c = i2 >> 6, d2 = i2 & 63;
        float iv = cgp[c * 260 + d2] + cbs[d2];
        float fv = cgp[c * 260 + 64 + d2] + cbs[64 + d2];
        float gv = cgp[c * 260 + 128 + d2] + cbs[128 + d2];
        float ov = cgp[c * 260 + 192 + d2] + cbs[192 + d2];
        float cn = sigf(fv) * ccl[i2] + sigf(iv) * tanhf_(gv);
        ccl[i2] = cn;
        chl[i2] = sigf(ov) * tanhf_(cn);
      }
      __syncthreads();
      cmsgPhase();   // next step's gate const
    }
  }

  // ---- vote: h of own 64 rows is in A-tile cols 0..63 ----
  {
    int r = tid >> 2, p = tid & 3;
    float hj[4] = {0.f, 0.f, 0.f, 0.f};
    for (int d2 = 0; d2 < 64; ++d2) {
      float hv = b2f(AtileU[r * 136 + d2]);
#pragma unroll
      for (int jj = 0; jj < 4; ++jj) hj[jj] += hv * W1v[(p * 4 + jj) * 64 + d2];
    }
    float pv = 0.f;
#pragma unroll
    for (int jj = 0; jj < 4; ++jj) pv += sigf(hj[jj] + b1v[p * 4 + jj]) * W2v[p * 4 + jj];
    vot[tid] = pv;
  }
  __syncthreads();
  if (tid < 64) {
    float vr = vot[tid * 4] + vot[tid * 4 + 1] + vot[tid * 4 + 2] + vot[tid * 4 + 3] + A.vob2[0];
    vr += __shfl_xor(vr, 1);
    vr += __shfl_xor(vr, 2);
    vr += __shfl_xor(vr, 4);
    vr += __shfl_xor(vr, 8);
    vr += __shfl_xor(vr, 16);
    vr += __shfl_xor(vr, 32);
    if (tid == 0) atomicAdd(&A.voteAcc[bb], vr);
  }
  gridbar(A.bar, (++ep) * GBLK);
  if (blockIdx.x < 8 && tid == 0) {
    float m = A.voteAcc[blockIdx.x] * (1.f / 2048.f);
    A.out[blockIdx.x] = 1.f / (1.f + __expf(-m));
  }
}

// ---------- host ----------
extern "C" void kernel_launch(void* const* d_in, const int* in_sizes, int n_in,
                              void* d_out, int out_size, void* d_ws, size_t ws_size,
                              hipStream_t stream) {
  (void)in_sizes; (void)n_in; (void)out_size; (void)ws_size;
  const float* Mvv    = (const float*)d_in[0];
  const float* chInit = (const float*)d_in[1];
  const float* vInit  = (const float*)d_in[2];
  const float* vWih   = (const float*)d_in[3];
  const float* vWhh   = (const float*)d_in[4];
  const float* vbih   = (const float*)d_in[5];
  const float* vbhh   = (const float*)d_in[6];
  const float* cWih   = (const float*)d_in[7];
  const float* cWhh   = (const float*)d_in[8];
  const float* cbih   = (const float*)d_in[9];
  const float* cbhh   = (const float*)d_in[10];
  const float* cm1    = (const float*)d_in[11];
  const float* cmb1   = (const float*)d_in[12];
  const float* cm2    = (const float*)d_in[13];
  const float* cmb2   = (const float*)d_in[14];
  const float* vm1    = (const float*)d_in[15];
  const float* vmb1   = (const float*)d_in[16];
  const float* vm2    = (const float*)d_in[17];
  const float* vmb2   = (const float*)d_in[18];
  const float* voW1   = (const float*)d_in[19];
  const float* vob1   = (const float*)d_in[20];
  const float* voW2   = (const float*)d_in[21];
  const float* vob2   = (const float*)d_in[22];
  const int*   ncol   = (const int*)d_in[23];

  char* wsb = (char*)d_ws;
  size_t off = 0;
  auto wsAlloc = [&](size_t bytes) -> char* {
    char* p = wsb + off;
    off = (off + bytes + 255) & ~(size_t)255;
    return p;
  };
  unsigned* bar          = (unsigned*)wsAlloc(256);   // +64: voteAcc
  float* voteAcc         = (float*)((char*)bar + 64);
  unsigned short* vhb    = (unsigned short*)wsAlloc((size_t)2 * Bk * Nk * Dk * 2);
  int* nbrCnt            = (int*)wsAlloc((size_t)Bk * Nk * 4);
  unsigned short* nbrIdx = (unsigned short*)wsAlloc((size_t)Bk * Nk * MAXD * 2);
  float* partial         = (float*)wsAlloc((size_t)2 * GBLK * 64 * 4);
  unsigned short* wcat   = (unsigned short*)wsAlloc(256 * 128 * 2);
  unsigned short* cwcat  = (unsigned short*)wsAlloc(256 * 128 * 2);
  unsigned short* vw1    = (unsigned short*)wsAlloc(112 * 64 * 2);
  unsigned short* vw2    = (unsigned short*)wsAlloc(64 * 128 * 2);
  unsigned short* cw1    = (unsigned short*)wsAlloc(112 * 64 * 2);
  unsigned short* cw2    = (unsigned short*)wsAlloc(64 * 128 * 2);

  k_init_w<<<1, 256, 0, stream>>>(vWih, vWhh, cWih, cWhh, vm1, vm2, cm1, cm2,
                                  wcat, cwcat, vw1, vw2, cw1, cw2, bar, voteAcc);
  k_init_vh<<<256, 256, 0, stream>>>(vInit, vhb);
  k_build<<<Bk * Nk / 4, 256, 0, stream>>>(Mvv, nbrIdx, nbrCnt);

  (void)hipFuncSetAttribute((const void*)k_persist,
                            hipFuncAttributeMaxDynamicSharedMemorySize, LDS_TOTAL);
  PArgs pa;
  pa.vWih = vWih; pa.chInit = chInit;
  pa.vbih = vbih; pa.vbhh = vbhh; pa.cbih = cbih; pa.cbhh = cbhh;
  pa.vmb1 = vmb1; pa.vmb2 = vmb2; pa.cmb1 = cmb1; pa.cmb2 = cmb2;
  pa.voW1 = voW1; pa.vob1 = vob1; pa.voW2 = voW2; pa.vob2 = vob2;
  pa.ncolors = ncol;
  pa.vhbuf = vhb; pa.nbrCnt = nbrCnt; pa.nbrIdx = nbrIdx; pa.partial = partial;
  pa.wcat = wcat; pa.cwcat = cwcat; pa.vw1 = vw1; pa.vw2 = vw2; pa.cw1 = cw1; pa.cw2 = cw2;
  pa.bar = bar; pa.voteAcc = voteAcc; pa.out = (float*)d_out;
  k_persist<<<GBLK, 256, LDS_TOTAL, stream>>>(pa);
}

// Round 3
// 1829.110 us; speedup vs baseline: 3.3175x; 3.3175x over previous
//
#include <hip/hip_runtime.h>

#define Bk 8
#define Nk 2048
#define Ck 16
#define Dk 64
#define Tk 32
#define GBLK 256
#define SLOT (Bk * 64 * 2048)   // ushorts per vh_t slot

typedef __attribute__((ext_vector_type(8))) short short8;
typedef __attribute__((ext_vector_type(4))) float floatx4;
typedef unsigned long long u64;
typedef unsigned short u16;

// ---------- LDS layout (dynamic, one block/CU) ----------
#define OFF_WCAT 0           // [256][136] bf16  vertex gate weights (Wih_left|Whh)
#define OFF_VW1  69632       // [112][72]  bf16  vmsg W1 (padded 100->112)
#define OFF_VW2  85760       // [64][136]  bf16  vmsg W2 (K padded 100->128, zeros)
#define OFF_AT   103168      // [64][136]  bf16  A-tile / chunk buf 0
#define OFF_HT   120576      // [64][136]  bf16  H-tile / chunk buf 1
#define OFF_CH   137984      // [16][64] f32 ch (block-local color state)
#define OFF_CC   142080      // [16][64] f32 cc
#define OFF_GC   146176      // [256] f32 gate const (cm term + biases)
#define OFF_VBS  147200      // [256] f32 v_bih+v_bhh
#define OFF_CBS  148224      // [256] f32 c_bih+c_bhh
#define OFF_VB1  149248      // [112] f32
#define OFF_VB2  149760      // [64]  f32
#define OFF_CB1  150016      // [112] f32
#define OFF_CB2  150528      // [64]  f32
#define OFF_W1V  150784      // [16][64] f32 vote W1
#define OFF_B1V  154880      // [16] f32
#define OFF_W2V  154944      // [16] f32
#define OFF_VAC  155008      // [64] f32 vmsg accum (LDS atomics)
#define OFF_VMS  155264      // [64] f32 vmsg_sum (batch)
#define OFF_CMS  155520      // [64] f32 cm_sum
#define OFF_VOT  155776      // [256] f32 vote scratch
#define LDS_TOTAL 156800

__device__ __forceinline__ float b2f(u16 u) {
  return __uint_as_float(((unsigned)u) << 16);
}
__device__ __forceinline__ u16 f2b(float f) {
  unsigned u = __float_as_uint(f);
  unsigned r = (u + 0x7FFFu + ((u >> 16) & 1u)) >> 16;
  return (u16)r;
}
__device__ __forceinline__ float sigf(float x) { return 1.0f / (1.0f + __expf(-x)); }
__device__ __forceinline__ float tanhf_(float x) { return 2.0f / (1.0f + __expf(-2.0f * x)) - 1.0f; }

// agent-scope (cross-XCD coherent) helpers: stores write through L2, loads bypass to MALL
__device__ __forceinline__ void s_agent_u64(u64* p, u64 v) {
  __hip_atomic_store(p, v, __ATOMIC_RELAXED, __HIP_MEMORY_SCOPE_AGENT);
}
__device__ __forceinline__ u64 l_agent_u64(const u64* p) {
  return __hip_atomic_load(p, __ATOMIC_RELAXED, __HIP_MEMORY_SCOPE_AGENT);
}
__device__ __forceinline__ void s_agent_f32(float* p, float v) {
  __hip_atomic_store(p, v, __ATOMIC_RELAXED, __HIP_MEMORY_SCOPE_AGENT);
}
__device__ __forceinline__ float l_agent_f32(const float* p) {
  return __hip_atomic_load(p, __ATOMIC_RELAXED, __HIP_MEMORY_SCOPE_AGENT);
}

// ---------- one-time init kernels ----------
__global__ void k_init_w(const float* vWih, const float* vWhh, const float* cWih, const float* cWhh,
                         const float* vm1, const float* vm2, const float* cm1, const float* cm2,
                         u16* wcat, u16* cwcat, u16* vw1, u16* vw2, u16* cw1, u16* cw2,
                         unsigned* bar, float* voteAcc, u64* diagBits) {
  const int tid = threadIdx.x;
  for (int i = tid; i < 256 * 128; i += 256) {
    int g = i >> 7, k = i & 127;
    wcat[i]  = f2b(k < 64 ? vWih[g * 128 + k] : vWhh[g * 64 + (k - 64)]);
    cwcat[i] = f2b(k < 64 ? cWih[g * 64 + k]  : cWhh[g * 64 + (k - 64)]);
  }
  for (int i = tid; i < 112 * 64; i += 256) {
    int j = i >> 6, k = i & 63;
    vw1[i] = f2b(j < 100 ? vm1[j * 64 + k] : 0.f);
    cw1[i] = f2b(j < 100 ? cm1[j * 64 + k] : 0.f);
  }
  for (int i = tid; i < 64 * 128; i += 256) {
    int d = i >> 7, k = i & 127;
    vw2[i] = f2b(k < 100 ? vm2[d * 100 + k] : 0.f);
    cw2[i] = f2b(k < 100 ? cm2[d * 100 + k] : 0.f);
  }
  if (tid == 0) *bar = 0u;
  if (tid < 8) voteAcc[tid] = 0.f;
  if (tid < 256) diagBits[tid] = 0ull;   // [B][32]
}

// vh_t slot 0 = v_init broadcast, layout [b][d][n]
__global__ void k_init_vt(const float* vInit, u16* vt0) {
  for (int i = blockIdx.x * blockDim.x + threadIdx.x; i < SLOT; i += gridDim.x * blockDim.x) {
    int d = (i >> 11) & 63;
    vt0[i] = f2b(vInit[d]);
  }
}

// bit-pack A = Mvv(+I); diag flag (Mvv[r][r]) separately. One wave per row.
__global__ void k_bits(const float* Mvv, u64* Abits, u64* diagBits) {
  const int lane = threadIdx.x & 63;
  const int wid = blockIdx.x * 4 + (threadIdx.x >> 6);   // global row in [0, B*N)
  const int b = wid >> 11, n = wid & 2047;
  const float* row = Mvv + (size_t)wid * Nk;
  u64* dst = Abits + (size_t)wid * 32;
  for (int w64 = 0; w64 < 32; ++w64) {
    float v = row[w64 * 64 + lane];
    u64 m = __ballot(v != 0.0f);
    if (lane == 0) {
      if (w64 == (n >> 6)) {
        if ((m >> (n & 63)) & 1ull)   // Mvv has a self edge -> diag weight 2
          atomicOr(diagBits + b * 32 + (n >> 6), 1ull << (n & 63));
        m |= 1ull << (n & 63);        // +I self loop
      }
      dst[w64] = m;
    }
  }
}

// ---------- persistent kernel ----------
struct PArgs {
  const float *vWih, *chInit;
  const float *vbih, *vbhh, *cbih, *cbhh;
  const float *vmb1, *vmb2, *cmb1, *cmb2;
  const float *voW1, *vob1, *voW2, *vob2;
  const int* ncolors;
  u16* vhbuf;                    // [2][B][64][2048] bf16, transposed layout
  const u64* Abits;              // [B][2048][32]
  const u64* diagBits;           // [B][32]
  float* partial;                // [2][GBLK][64]
  const u16 *wcat, *cwcat, *vw1, *vw2, *cw1, *cw2;
  unsigned* bar;
  float* voteAcc;
  float* out;
};

__device__ __forceinline__ void gridbar(unsigned* bar, unsigned target) {
  __syncthreads();   // compiler drains vmcnt(0) here -> all prior WT stores are at MALL
  if (threadIdx.x == 0) {
    atomicAdd(bar, 1u);
    int guard = 0;
    while (__hip_atomic_load(bar, __ATOMIC_RELAXED, __HIP_MEMORY_SCOPE_AGENT) < target) {
      __builtin_amdgcn_s_sleep(2);
      if (++guard > (1 << 24)) break;
    }
  }
  __syncthreads();
}

__global__ void __launch_bounds__(256, 1) k_persist(PArgs A) {
  extern __shared__ char smem[];
  u16* WcatU  = (u16*)(smem + OFF_WCAT);
  u16* vW1U   = (u16*)(smem + OFF_VW1);
  u16* vW2U   = (u16*)(smem + OFF_VW2);
  u16* AtileU = (u16*)(smem + OFF_AT);
  u16* HtileU = (u16*)(smem + OFF_HT);
  float* chl = (float*)(smem + OFF_CH);
  float* ccl = (float*)(smem + OFF_CC);
  float* gc  = (float*)(smem + OFF_GC);
  float* vbs = (float*)(smem + OFF_VBS);
  float* cbs = (float*)(smem + OFF_CBS);
  float* vb1 = (float*)(smem + OFF_VB1);
  float* vb2 = (float*)(smem + OFF_VB2);
  float* cb1 = (float*)(smem + OFF_CB1);
  float* cb2 = (float*)(smem + OFF_CB2);
  float* W1v = (float*)(smem + OFF_W1V);
  float* b1v = (float*)(smem + OFF_B1V);
  float* W2v = (float*)(smem + OFF_W2V);
  float* vac = (float*)(smem + OFF_VAC);
  float* vms = (float*)(smem + OFF_VMS);
  float* cms = (float*)(smem + OFF_CMS);
  float* vot = (float*)(smem + OFF_VOT);

  const int tid = threadIdx.x;
  const int lane = tid & 63;
  const int w = tid >> 6;          // wave id 0..3 == M-tile
  const int q = lane >> 4;         // quad
  const int l15 = lane & 15;
  const int bb = blockIdx.x & 7;             // batch
  const int rb = (blockIdx.x >> 3) * 64;     // row base within batch
  const int ncolv = A.ncolors[bb];
  const floatx4 zf = {0.f, 0.f, 0.f, 0.f};

  // ---- stage weights/biases/state into LDS (once) ----
  for (int i = tid; i < 256 * 128; i += 256) { int g = i >> 7, k = i & 127; WcatU[g * 136 + k] = A.wcat[i]; }
  for (int i = tid; i < 112 * 64; i += 256)  { int j = i >> 6, k = i & 63;  vW1U[j * 72 + k]  = A.vw1[i]; }
  for (int i = tid; i < 64 * 128; i += 256)  { int d = i >> 7, k = i & 127; vW2U[d * 136 + k] = A.vw2[i]; }
  if (tid < 112) { vb1[tid] = (tid < 100) ? A.vmb1[tid] : 0.f; cb1[tid] = (tid < 100) ? A.cmb1[tid] : 0.f; }
  if (tid < 64)  { vb2[tid] = A.vmb2[tid]; cb2[tid] = A.cmb2[tid]; vac[tid] = 0.f; }
  vbs[tid] = A.vbih[tid] + A.vbhh[tid];
  cbs[tid] = A.cbih[tid] + A.cbhh[tid];
  for (int i = tid; i < 1024; i += 256) { W1v[i] = A.voW1[i]; chl[i] = A.chInit[bb * 1024 + i]; ccl[i] = 0.f; }
  if (tid < 16) { b1v[tid] = A.vob1[tid]; W2v[tid] = A.voW2[tid]; }
  const u64 diagbits = A.diagBits[bb * 32 + (rb >> 6)];
  __syncthreads();

  // c_msg MLP (on current chl) + cm_sum + vertex-gate-const. Redundant per block.
  // Uses AtileU/HtileU as scratch (free between steps).
  auto cmsgPhase = [&]() {
    for (int i = tid; i < 1024; i += 256) { int c = i >> 6, kk = i & 63; AtileU[c * 136 + kk] = f2b(chl[i]); }
    __syncthreads();
    floatx4 m1a = zf, m1b = zf;
#pragma unroll
    for (int ks = 0; ks < 2; ++ks) {
      short8 af = *(const short8*)(AtileU + l15 * 136 + ks * 32 + q * 8);
      short8 b0 = *(const short8*)(A.cw1 + (size_t)((w * 16 + l15) * 64 + ks * 32 + q * 8));
      m1a = __builtin_amdgcn_mfma_f32_16x16x32_bf16(af, b0, m1a, 0, 0, 0);
      if (w < 3) {
        short8 b1 = *(const short8*)(A.cw1 + (size_t)(((w + 4) * 16 + l15) * 64 + ks * 32 + q * 8));
        m1b = __builtin_amdgcn_mfma_f32_16x16x32_bf16(af, b1, m1b, 0, 0, 0);
      }
    }
#pragma unroll
    for (int reg = 0; reg < 4; ++reg) {
      float hv = m1a[reg] + cb1[w * 16 + l15];
      HtileU[(q * 4 + reg) * 136 + w * 16 + l15] = f2b(hv > 0.f ? hv : 0.f);
    }
    if (w < 3) {
#pragma unroll
      for (int reg = 0; reg < 4; ++reg) {
        float hv = m1b[reg] + cb1[(w + 4) * 16 + l15];
        HtileU[(q * 4 + reg) * 136 + (w + 4) * 16 + l15] = f2b(hv > 0.f ? hv : 0.f);
      }
    }
    // zero cols 112..127 of the 16 used rows (K padding for the W2 GEMM)
    if (tid < 128) {
      int r = tid >> 3, c = 112 + (tid & 7) * 2;
      HtileU[r * 136 + c] = 0; HtileU[r * 136 + c + 1] = 0;
    }
    __syncthreads();
    floatx4 m2 = zf;
#pragma unroll
    for (int ks = 0; ks < 4; ++ks) {
      short8 af = *(const short8*)(HtileU + l15 * 136 + ks * 32 + q * 8);
      short8 bv = *(const short8*)(A.cw2 + (size_t)((w * 16 + l15) * 128 + ks * 32 + q * 8));
      m2 = __builtin_amdgcn_mfma_f32_16x16x32_bf16(af, bv, m2, 0, 0, 0);
    }
    float s2 = 0.f;
#pragma unroll
    for (int reg = 0; reg < 4; ++reg) {
      int c = q * 4 + reg;
      float v = m2[reg] + cb2[w * 16 + l15];
      v = v > 0.f ? v : 0.f;
      if (c < ncolv) s2 += v;
    }
    s2 += __shfl_xor(s2, 16);
    s2 += __shfl_xor(s2, 32);
    if (q == 0) cms[w * 16 + l15] = s2;
    __syncthreads();
    {
      float dot = 0.f;
      const float* wr = A.vWih + tid * 128 + 64;    // right half of v_Wih (cm_sum input)
      for (int k2 = 0; k2 < 64; ++k2) dot += cms[k2] * wr[k2];
      gc[tid] = dot + vbs[tid];
    }
    __syncthreads();
  };

  float vc[4][4] = {};          // vertex cell state (fp32, regs)
  u16 hreg[16];                 // own rows' h_prev, lane = d
  {
    u16 h0 = f2b(A.vWih == nullptr ? 0.f : 0.f);  // placeholder, overwritten below
    (void)h0;
  }
  {
    float vi = ((const float*)A.voW1, 0.f);  (void)vi;
  }
  // h_prev(t=0) = v_init[d]
  {
    // v_init is staged via vhbuf slot0; read own value once (agent not needed: slot0 from init kernel)
    u16 h0 = A.vhbuf[(size_t)(bb * 64 + lane) * 2048 + rb];   // [d][n=rb] == v_init[d]
#pragma unroll
    for (int r = 0; r < 16; ++r) hreg[r] = h0;
  }

  cmsgPhase();                  // prologue: gate const from ch_init
  unsigned ep = 0;

  const u64* arow = A.Abits + ((size_t)bb * 2048 + rb + w * 16 + l15) * 32;

  for (int t = 0; t < Tk; ++t) {
    const u16* vtr = A.vhbuf + (size_t)(t & 1) * SLOT + (size_t)bb * 64 * 2048;
    u16* vtw = A.vhbuf + (size_t)((t & 1) ^ 1) * SLOT + (size_t)bb * 64 * 2048;

    // ================= a1: Avh = (Mvv+I) @ vh via bit-MFMA over 16 chunks =================
    floatx4 acc4[4];
#pragma unroll
    for (int nt = 0; nt < 4; ++nt) acc4[nt] = zf;

    u64 regs[8];
    // prefetch chunk 0 (agent loads: other blocks' writes live at MALL)
#pragma unroll
    for (int i = 0; i < 8; ++i) {
      int f = i * 256 + tid, d = f >> 5, j4 = f & 31;
      regs[i] = l_agent_u64((const u64*)(vtr + (size_t)d * 2048 + 0 * 128 + j4 * 4));
    }
    for (int c = 0; c < 16; ++c) {
      u16* buf = (c & 1) ? HtileU : AtileU;
      __syncthreads();    // buf free (chunk c-2 consumed)
#pragma unroll
      for (int i = 0; i < 8; ++i) {
        int f = i * 256 + tid, d = f >> 5, j4 = f & 31;
        *(u64*)(buf + d * 136 + j4 * 4) = regs[i];
      }
      if (c < 15) {
#pragma unroll
        for (int i = 0; i < 8; ++i) {
          int f = i * 256 + tid, d = f >> 5, j4 = f & 31;
          regs[i] = l_agent_u64((const u64*)(vtr + (size_t)d * 2048 + (c + 1) * 128 + j4 * 4));
        }
      }
      __syncthreads();    // buf ready
      u64 w0 = arow[c * 2], w1 = arow[c * 2 + 1];
#pragma unroll
      for (int ks = 0; ks < 4; ++ks) {
        unsigned byte = (unsigned)(((ks & 2) ? w1 : w0) >> ((ks & 1) * 32 + q * 8)) & 0xFFu;
        short8 af;
#pragma unroll
        for (int j = 0; j < 8; ++j) af[j] = (short)(((byte >> j) & 1u) ? 0x3F80 : 0);
#pragma unroll
        for (int nt = 0; nt < 4; ++nt) {
          short8 bv = *(const short8*)(buf + (nt * 16 + l15) * 136 + ks * 32 + q * 8);
          acc4[nt] = __builtin_amdgcn_mfma_f32_16x16x32_bf16(af, bv, acc4[nt], 0, 0, 0);
        }
      }
    }
    __syncthreads();  // all chunk compute done; A/H tiles free

    // write h_prev into A-tile cols 64..127 (lane = d, own rows — wave-local)
#pragma unroll
    for (int r = 0; r < 16; ++r) AtileU[(w * 16 + r) * 136 + 64 + lane] = hreg[r];
    // diag extra add (+1 more copy of h_prev where Mvv[r][r]=1), then write Avh cols 0..63
#pragma unroll
    for (int nt = 0; nt < 4; ++nt) {
#pragma unroll
      for (int reg = 0; reg < 4; ++reg) {
        int m = w * 16 + q * 4 + reg;
        float fl = (float)((diagbits >> m) & 1ull);
        float hp = b2f(AtileU[m * 136 + 64 + nt * 16 + l15]);
        AtileU[m * 136 + nt * 16 + l15] = f2b(acc4[nt][reg] + fl * hp);
      }
    }

    // ---- a2: gates = [Avh|vh] @ Wcat^T  (wave-local reads of own rows)
    floatx4 acc[16];
#pragma unroll
    for (int nt = 0; nt < 16; ++nt) acc[nt] = zf;
#pragma unroll
    for (int ks = 0; ks < 4; ++ks) {
      short8 af = *(const short8*)(AtileU + (w * 16 + l15) * 136 + ks * 32 + q * 8);
#pragma unroll
      for (int nt = 0; nt < 16; ++nt) {
        short8 bv = *(const short8*)(WcatU + (nt * 16 + l15) * 136 + ks * 32 + q * 8);
        acc[nt] = __builtin_amdgcn_mfma_f32_16x16x32_bf16(af, bv, acc[nt], 0, 0, 0);
      }
    }

    // ---- a3/a4: LSTM pointwise; h -> A-tile cols 0..63
#pragma unroll
    for (int u = 0; u < 4; ++u) {
      const int d2 = u * 16 + l15;
      const float gi = gc[d2], gf2 = gc[64 + d2], gg = gc[128 + d2], go = gc[192 + d2];
#pragma unroll
      for (int reg = 0; reg < 4; ++reg) {
        float iv = acc[u][reg] + gi;
        float fv = acc[u + 4][reg] + gf2;
        float gv = acc[u + 8][reg] + gg;
        float ov = acc[u + 12][reg] + go;
        float cn = sigf(fv) * vc[u][reg] + sigf(iv) * tanhf_(gv);
        vc[u][reg] = cn;
        AtileU[(w * 16 + q * 4 + reg) * 136 + d2] = f2b(sigf(ov) * tanhf_(cn));
      }
    }
    // snapshot own h for next step (wave-local LDS, ordered within wave)
#pragma unroll
    for (int r = 0; r < 16; ++r) hreg[r] = AtileU[(w * 16 + r) * 136 + lane];

    // ---- a5: v_msg hidden = relu(h @ W1^T + b1)  (wave-local)
    floatx4 h1[7];
#pragma unroll
    for (int nt = 0; nt < 7; ++nt) h1[nt] = zf;
#pragma unroll
    for (int ks = 0; ks < 2; ++ks) {
      short8 af = *(const short8*)(AtileU + (w * 16 + l15) * 136 + ks * 32 + q * 8);
#pragma unroll
      for (int nt = 0; nt < 7; ++nt) {
        short8 bv = *(const short8*)(vW1U + (nt * 16 + l15) * 72 + ks * 32 + q * 8);
        h1[nt] = __builtin_amdgcn_mfma_f32_16x16x32_bf16(af, bv, h1[nt], 0, 0, 0);
      }
    }
#pragma unroll
    for (int nt = 0; nt < 7; ++nt) {
      float bb1 = vb1[nt * 16 + l15];
#pragma unroll
      for (int reg = 0; reg < 4; ++reg) {
        float hv = h1[nt][reg] + bb1;
        HtileU[(w * 16 + q * 4 + reg) * 136 + nt * 16 + l15] = f2b(hv > 0.f ? hv : 0.f);
      }
    }
    // zero K-padding cols 112..127 of own rows
#pragma unroll
    for (int r = 0; r < 4; ++r) {
      int rr = w * 16 + q * 4 + r;
      HtileU[rr * 136 + 112 + l15] = 0;
    }

    // ---- a6: v_msg = relu(hidden @ W2^T + b2); reduce over rows
    floatx4 vm[4];
#pragma unroll
    for (int nt = 0; nt < 4; ++nt) vm[nt] = zf;
#pragma unroll
    for (int ks = 0; ks < 4; ++ks) {
      short8 af = *(const short8*)(HtileU + (w * 16 + l15) * 136 + ks * 32 + q * 8);
#pragma unroll
      for (int nt = 0; nt < 4; ++nt) {
        short8 bv = *(const short8*)(vW2U + (nt * 16 + l15) * 136 + ks * 32 + q * 8);
        vm[nt] = __builtin_amdgcn_mfma_f32_16x16x32_bf16(af, bv, vm[nt], 0, 0, 0);
      }
    }
#pragma unroll
    for (int u = 0; u < 4; ++u) {
      float bb2 = vb2[u * 16 + l15];
      float s = 0.f;
#pragma unroll
      for (int reg = 0; reg < 4; ++reg) { float v = vm[u][reg] + bb2; s += (v > 0.f ? v : 0.f); }
      s += __shfl_xor(s, 16);
      s += __shfl_xor(s, 32);
      if (q == 0) atomicAdd(&vac[u * 16 + l15], s);
    }
    __syncthreads();   // all waves' LSTM h in A-tile + vac complete

    // ---- publish: block partial (agent WT) + vh_new transposed [d][n] (agent WT)
    if (tid < 64) s_agent_f32(&A.partial[(size_t)((t & 1) * GBLK + blockIdx.x) * 64 + tid], vac[tid]);
#pragma unroll
    for (int ii = 0; ii < 4; ++ii) {
      int u = tid + ii * 256;            // 0..1023
      int d = u >> 4, r4 = (u & 15) * 4;
      u64 val = 0;
#pragma unroll
      for (int j = 0; j < 4; ++j) val |= ((u64)AtileU[(r4 + j) * 136 + d]) << (16 * j);
      s_agent_u64((u64*)(vtw + (size_t)d * 2048 + rb + r4), val);
    }
    __syncthreads();
    if (tid < 64) vac[tid] = 0.f;

    gridbar(A.bar, (++ep) * GBLK);

    if (t < Tk - 1) {
      // ---- color phase (redundant per block, local ch/cc) ----
      if (tid < 64) {
        float s = 0.f;
        const float* pp = A.partial + (size_t)((t & 1) * GBLK) * 64;
        for (int i2 = 0; i2 < 32; ++i2) s += l_agent_f32(&pp[(i2 * 8 + bb) * 64 + tid]);
        vms[tid] = s;
      }
      __syncthreads();
      for (int i2 = tid; i2 < 16 * 128; i2 += 256) {
        int c = i2 >> 7, kk = i2 & 127;
        float v = (kk < 64) ? ((c < ncolv) ? vms[kk] : 0.f) : chl[c * 64 + (kk - 64)];
        AtileU[c * 136 + kk] = f2b(v);
      }
      __syncthreads();
      floatx4 cacc[4];
#pragma unroll
      for (int j = 0; j < 4; ++j) cacc[j] = zf;
#pragma unroll
      for (int ks = 0; ks < 4; ++ks) {
        short8 af = *(const short8*)(AtileU + l15 * 136 + ks * 32 + q * 8);
#pragma unroll
        for (int j = 0; j < 4; ++j) {
          short8 bv = *(const short8*)(A.cwcat + (size_t)(((w * 4 + j) * 16 + l15) * 128 + ks * 32 + q * 8));
          cacc[j] = __builtin_amdgcn_mfma_f32_16x16x32_bf16(af, bv, cacc[j], 0, 0, 0);
        }
      }
      __syncthreads();
      float* cgp = (float*)(smem + OFF_AT);   // fp32 overlay for gate exchange
#pragma unroll
      for (int j = 0; j < 4; ++j)
#pragma unroll
        for (int reg = 0; reg < 4; ++reg)
          cgp[(q * 4 + reg) * 260 + (w * 4 + j) * 16 + l15] = cacc[j][reg];
      __syncthreads();
      for (int i2 = tid; i2 < 1024; i2 += 256) {
        int c = i2 >> 6, d2 = i2 & 63;
        float iv = cgp[c * 260 + d2] + cbs[d2];
        float fv = cgp[c * 260 + 64 + d2] + cbs[64 + d2];
        float gv = cgp[c * 260 + 128 + d2] + cbs[128 + d2];
        float ov = cgp[c * 260 + 192 + d2] + cbs[192 + d2];
        float cn = sigf(fv) * ccl[i2] + sigf(iv) * tanhf_(gv);
        ccl[i2] = cn;
        chl[i2] = sigf(ov) * tanhf_(cn);
      }
      __syncthreads();
      cmsgPhase();   // next step's gate const
    }
  }

  // ---- vote: h of own 64 rows is in A-tile cols 0..63 ----
  {
    int r = tid >> 2, p = tid & 3;
    float hj[4] = {0.f, 0.f, 0.f, 0.f};
    for (int d2 = 0; d2 < 64; ++d2) {
      float hv = b2f(AtileU[r * 136 + d2]);
#pragma unroll
      for (int jj = 0; jj < 4; ++jj) hj[jj] += hv * W1v[(p * 4 + jj) * 64 + d2];
    }
    float pv = 0.f;
#pragma unroll
    for (int jj = 0; jj < 4; ++jj) pv += sigf(hj[jj] + b1v[p * 4 + jj]) * W2v[p * 4 + jj];
    vot[tid] = pv;
  }
  __syncthreads();
  if (tid < 64) {
    float vr = vot[tid * 4] + vot[tid * 4 + 1] + vot[tid * 4 + 2] + vot[tid * 4 + 3] + A.vob2[0];
    vr += __shfl_xor(vr, 1);
    vr += __shfl_xor(vr, 2);
    vr += __shfl_xor(vr, 4);
    vr += __shfl_xor(vr, 8);
    vr += __shfl_xor(vr, 16);
    vr += __shfl_xor(vr, 32);
    if (tid == 0) atomicAdd(&A.voteAcc[bb], vr);
  }
  gridbar(A.bar, (++ep) * GBLK);
  if (blockIdx.x < 8 && tid == 0) {
    float m = l_agent_f32(&A.voteAcc[blockIdx.x]) * (1.f / 2048.f);
    A.out[blockIdx.x] = 1.f / (1.f + __expf(-m));
  }
}

// ---------- host ----------
extern "C" void kernel_launch(void* const* d_in, const int* in_sizes, int n_in,
                              void* d_out, int out_size, void* d_ws, size_t ws_size,
                              hipStream_t stream) {
  (void)in_sizes; (void)n_in; (void)out_size; (void)ws_size;
  const float* Mvv    = (const float*)d_in[0];
  const float* chInit = (const float*)d_in[1];
  const float* vInit  = (const float*)d_in[2];
  const float* vWih   = (const float*)d_in[3];
  const float* vWhh   = (const float*)d_in[4];
  const float* vbih   = (const float*)d_in[5];
  const float* vbhh   = (const float*)d_in[6];
  const float* cWih   = (const float*)d_in[7];
  const float* cWhh   = (const float*)d_in[8];
  const float* cbih   = (const float*)d_in[9];
  const float* cbhh   = (const float*)d_in[10];
  const float* cm1    = (const float*)d_in[11];
  const float* cmb1   = (const float*)d_in[12];
  const float* cm2    = (const float*)d_in[13];
  const float* cmb2   = (const float*)d_in[14];
  const float* vm1    = (const float*)d_in[15];
  const float* vmb1   = (const float*)d_in[16];
  const float* vm2    = (const float*)d_in[17];
  const float* vmb2   = (const float*)d_in[18];
  const float* voW1   = (const float*)d_in[19];
  const float* vob1   = (const float*)d_in[20];
  const float* voW2   = (const float*)d_in[21];
  const float* vob2   = (const float*)d_in[22];
  const int*   ncol   = (const int*)d_in[23];

  char* wsb = (char*)d_ws;
  size_t off = 0;
  auto wsAlloc = [&](size_t bytes) -> char* {
    char* p = wsb + off;
    off = (off + bytes + 255) & ~(size_t)255;
    return p;
  };
  unsigned* bar   = (unsigned*)wsAlloc(256);
  float* voteAcc  = (float*)((char*)bar + 64);
  u16* vhb        = (u16*)wsAlloc((size_t)2 * SLOT * 2);               // 4 MB
  u64* Abits      = (u64*)wsAlloc((size_t)Bk * Nk * 32 * 8);           // 4 MB
  u64* diagBits   = (u64*)wsAlloc((size_t)Bk * 32 * 8);                // 2 KB
  float* partial  = (float*)wsAlloc((size_t)2 * GBLK * 64 * 4);        // 128 KB
  u16* wcat       = (u16*)wsAlloc(256 * 128 * 2);
  u16* cwcat      = (u16*)wsAlloc(256 * 128 * 2);
  u16* vw1        = (u16*)wsAlloc(112 * 64 * 2);
  u16* vw2        = (u16*)wsAlloc(64 * 128 * 2);
  u16* cw1        = (u16*)wsAlloc(112 * 64 * 2);
  u16* cw2        = (u16*)wsAlloc(64 * 128 * 2);

  k_init_w<<<1, 256, 0, stream>>>(vWih, vWhh, cWih, cWhh, vm1, vm2, cm1, cm2,
                                  wcat, cwcat, vw1, vw2, cw1, cw2, bar, voteAcc, diagBits);
  k_init_vt<<<256, 256, 0, stream>>>(vInit, vhb);
  k_bits<<<Bk * Nk / 4, 256, 0, stream>>>(Mvv, Abits, diagBits);

  (void)hipFuncSetAttribute((const void*)k_persist,
                            hipFuncAttributeMaxDynamicSharedMemorySize, LDS_TOTAL);
  PArgs pa;
  pa.vWih = vWih; pa.chInit = chInit;
  pa.vbih = vbih; pa.vbhh = vbhh; pa.cbih = cbih; pa.cbhh = cbhh;
  pa.vmb1 = vmb1; pa.vmb2 = vmb2; pa.cmb1 = cmb1; pa.cmb2 = cmb2;
  pa.voW1 = voW1; pa.vob1 = vob1; pa.voW2 = voW2; pa.vob2 = vob2;
  pa.ncolors = ncol;
  pa.vhbuf = vhb; pa.Abits = Abits; pa.diagBits = diagBits; pa.partial = partial;
  pa.wcat = wcat; pa.cwcat = cwcat; pa.vw1 = vw1; pa.vw2 = vw2; pa.cw1 = cw1; pa.cw2 = cw2;
  pa.bar = bar; pa.voteAcc = voteAcc; pa.out = (float*)d_out;
  k_persist<<<GBLK, 256, LDS_TOTAL, stream>>>(pa);
}

// Round 4
// 1792.766 us; speedup vs baseline: 3.3848x; 1.0203x over previous
//
#include <hip/hip_runtime.h>

#define Bk 8
#define Nk 2048
#define Ck 16
#define Dk 64
#define Tk 32
#define GBLK 256
#define SLOT (Bk * 64 * 2048)   // ushorts per vh_t slot

typedef __attribute__((ext_vector_type(8))) short short8;
typedef __attribute__((ext_vector_type(4))) float floatx4;
typedef unsigned long long u64;
typedef unsigned short u16;

// ---------- LDS layout (dynamic, one block/CU) ----------
#define OFF_WCAT 0           // [256][136] bf16  vertex gate weights (Wih_left|Whh)
#define OFF_VW1  69632       // [112][72]  bf16  vmsg W1 (padded 100->112)
#define OFF_VW2  85760       // [64][136]  bf16  vmsg W2 (K padded 100->128, zeros)
#define OFF_AT   103168      // [64][136]  bf16  A-tile / chunk buf 0
#define OFF_HT   120576      // [64][136]  bf16  H-tile / chunk buf 1
#define OFF_CH   137984      // [16][64] f32 ch (block-local color state)
#define OFF_CC   142080      // [16][64] f32 cc
#define OFF_GC   146176      // [256] f32 gate const (cm term + biases)
#define OFF_VBS  147200      // [256] f32 v_bih+v_bhh
#define OFF_CBS  148224      // [256] f32 c_bih+c_bhh
#define OFF_VB1  149248      // [112] f32
#define OFF_VB2  149760      // [64]  f32
#define OFF_CB1  150016      // [112] f32
#define OFF_CB2  150528      // [64]  f32
#define OFF_W1V  150784      // [16][64] f32 vote W1
#define OFF_B1V  154880      // [16] f32
#define OFF_W2V  154944      // [16] f32
#define OFF_VAC  155008      // [64] f32 vmsg accum (LDS atomics)
#define OFF_VMS  155264      // [64] f32 vmsg_sum (batch)
#define OFF_CMS  155520      // [64] f32 cm_sum
#define OFF_VOT  155776      // [256] f32 vote scratch
#define LDS_TOTAL 156800

// s_waitcnt imm: vmcnt(63) expcnt(7) lgkmcnt(0) -> lgkm-only wait, no VMEM drain
#define WAIT_LGKM0 0xC07F

__device__ __forceinline__ float b2f(u16 u) {
  return __uint_as_float(((unsigned)u) << 16);
}
__device__ __forceinline__ u16 f2b(float f) {
  unsigned u = __float_as_uint(f);
  unsigned r = (u + 0x7FFFu + ((u >> 16) & 1u)) >> 16;
  return (u16)r;
}
__device__ __forceinline__ float sigf(float x) { return 1.0f / (1.0f + __expf(-x)); }
__device__ __forceinline__ float tanhf_(float x) { return 2.0f / (1.0f + __expf(-2.0f * x)) - 1.0f; }

// agent-scope (cross-XCD coherent) helpers: stores write through, loads bypass to MALL
__device__ __forceinline__ void s_agent_u64(u64* p, u64 v) {
  __hip_atomic_store(p, v, __ATOMIC_RELAXED, __HIP_MEMORY_SCOPE_AGENT);
}
__device__ __forceinline__ u64 l_agent_u64(const u64* p) {
  return __hip_atomic_load(p, __ATOMIC_RELAXED, __HIP_MEMORY_SCOPE_AGENT);
}
__device__ __forceinline__ void s_agent_f32(float* p, float v) {
  __hip_atomic_store(p, v, __ATOMIC_RELAXED, __HIP_MEMORY_SCOPE_AGENT);
}
__device__ __forceinline__ float l_agent_f32(const float* p) {
  return __hip_atomic_load(p, __ATOMIC_RELAXED, __HIP_MEMORY_SCOPE_AGENT);
}

// lgkm-only wait + raw barrier (no vmcnt(0) drain, unlike __syncthreads)
__device__ __forceinline__ void barrier_nodrain() {
  asm volatile("" ::: "memory");
  __builtin_amdgcn_s_waitcnt(WAIT_LGKM0);
  __builtin_amdgcn_s_barrier();
  asm volatile("" ::: "memory");
}

// ---------- one-time init kernels ----------
__global__ void k_init_w(const float* vWih, const float* vWhh, const float* cWih, const float* cWhh,
                         const float* vm1, const float* vm2, const float* cm1, const float* cm2,
                         u16* wcat, u16* cwcat, u16* vw1, u16* vw2, u16* cw1, u16* cw2,
                         unsigned* bar, float* voteAcc, u64* diagBits) {
  const int tid = threadIdx.x;
  for (int i = tid; i < 256 * 128; i += 256) {
    int g = i >> 7, k = i & 127;
    wcat[i]  = f2b(k < 64 ? vWih[g * 128 + k] : vWhh[g * 64 + (k - 64)]);
    cwcat[i] = f2b(k < 64 ? cWih[g * 64 + k]  : cWhh[g * 64 + (k - 64)]);
  }
  for (int i = tid; i < 112 * 64; i += 256) {
    int j = i >> 6, k = i & 63;
    vw1[i] = f2b(j < 100 ? vm1[j * 64 + k] : 0.f);
    cw1[i] = f2b(j < 100 ? cm1[j * 64 + k] : 0.f);
  }
  for (int i = tid; i < 64 * 128; i += 256) {
    int d = i >> 7, k = i & 127;
    vw2[i] = f2b(k < 100 ? vm2[d * 100 + k] : 0.f);
    cw2[i] = f2b(k < 100 ? cm2[d * 100 + k] : 0.f);
  }
  if (tid == 0) *bar = 0u;
  if (tid < 8) voteAcc[tid] = 0.f;
  if (tid < 256) diagBits[tid] = 0ull;   // [B][32]
}

// vh_t slot 0 = v_init broadcast, layout [b][d][n]
__global__ void k_init_vt(const float* vInit, u16* vt0) {
  for (int i = blockIdx.x * blockDim.x + threadIdx.x; i < SLOT; i += gridDim.x * blockDim.x) {
    int d = (i >> 11) & 63;
    vt0[i] = f2b(vInit[d]);
  }
}

// bit-pack A = Mvv(+I); diag flag (Mvv[r][r]) separately. One wave per row.
__global__ void k_bits(const float* Mvv, u64* Abits, u64* diagBits) {
  const int lane = threadIdx.x & 63;
  const int wid = blockIdx.x * 4 + (threadIdx.x >> 6);   // global row in [0, B*N)
  const int b = wid >> 11, n = wid & 2047;
  const float* row = Mvv + (size_t)wid * Nk;
  u64* dst = Abits + (size_t)wid * 32;
  for (int w64 = 0; w64 < 32; ++w64) {
    float v = row[w64 * 64 + lane];
    u64 m = __ballot(v != 0.0f);
    if (lane == 0) {
      if (w64 == (n >> 6)) {
        if ((m >> (n & 63)) & 1ull)   // Mvv has a self edge -> diag weight 2
          atomicOr(diagBits + b * 32 + (n >> 6), 1ull << (n & 63));
        m |= 1ull << (n & 63);        // +I self loop
      }
      dst[w64] = m;
    }
  }
}

// ---------- persistent kernel ----------
struct PArgs {
  const float *vWih, *chInit;
  const float *vbih, *vbhh, *cbih, *cbhh;
  const float *vmb1, *vmb2, *cmb1, *cmb2;
  const float *voW1, *vob1, *voW2, *vob2;
  const int* ncolors;
  u16* vhbuf;                    // [2][B][64][2048] bf16, transposed layout
  const u64* Abits;              // [B][2048][32]
  const u64* diagBits;           // [B][32]
  float* partial;                // [2][GBLK][64]
  const u16 *wcat, *cwcat, *vw1, *vw2, *cw1, *cw2;
  unsigned* bar;
  float* voteAcc;
  float* out;
};

__device__ __forceinline__ void gridbar(unsigned* bar, unsigned target) {
  __syncthreads();   // drains vmcnt(0): all prior WT stores are at MALL before the flag
  if (threadIdx.x == 0) {
    atomicAdd(bar, 1u);
    int guard = 0;
    while (__hip_atomic_load(bar, __ATOMIC_RELAXED, __HIP_MEMORY_SCOPE_AGENT) < target) {
      __builtin_amdgcn_s_sleep(2);
      if (++guard > (1 << 24)) break;
    }
  }
  __syncthreads();
}

__global__ void __launch_bounds__(256, 1) k_persist(PArgs A) {
  extern __shared__ char smem[];
  u16* WcatU  = (u16*)(smem + OFF_WCAT);
  u16* vW1U   = (u16*)(smem + OFF_VW1);
  u16* vW2U   = (u16*)(smem + OFF_VW2);
  u16* AtileU = (u16*)(smem + OFF_AT);
  u16* HtileU = (u16*)(smem + OFF_HT);
  float* chl = (float*)(smem + OFF_CH);
  float* ccl = (float*)(smem + OFF_CC);
  float* gc  = (float*)(smem + OFF_GC);
  float* vbs = (float*)(smem + OFF_VBS);
  float* cbs = (float*)(smem + OFF_CBS);
  float* vb1 = (float*)(smem + OFF_VB1);
  float* vb2 = (float*)(smem + OFF_VB2);
  float* cb1 = (float*)(smem + OFF_CB1);
  float* cb2 = (float*)(smem + OFF_CB2);
  float* W1v = (float*)(smem + OFF_W1V);
  float* b1v = (float*)(smem + OFF_B1V);
  float* W2v = (float*)(smem + OFF_W2V);
  float* vac = (float*)(smem + OFF_VAC);
  float* vms = (float*)(smem + OFF_VMS);
  float* cms = (float*)(smem + OFF_CMS);
  float* vot = (float*)(smem + OFF_VOT);

  const int tid = threadIdx.x;
  const int lane = tid & 63;
  const int w = tid >> 6;          // wave id 0..3 == M-tile
  const int q = lane >> 4;         // quad
  const int l15 = lane & 15;
  const int bb = blockIdx.x & 7;             // batch
  const int rb = (blockIdx.x >> 3) * 64;     // row base within batch
  const int ncolv = A.ncolors[bb];
  const floatx4 zf = {0.f, 0.f, 0.f, 0.f};

  // ---- stage weights/biases/state into LDS (once) ----
  for (int i = tid; i < 256 * 128; i += 256) { int g = i >> 7, k = i & 127; WcatU[g * 136 + k] = A.wcat[i]; }
  for (int i = tid; i < 112 * 64; i += 256)  { int j = i >> 6, k = i & 63;  vW1U[j * 72 + k]  = A.vw1[i]; }
  for (int i = tid; i < 64 * 128; i += 256)  { int d = i >> 7, k = i & 127; vW2U[d * 136 + k] = A.vw2[i]; }
  if (tid < 112) { vb1[tid] = (tid < 100) ? A.vmb1[tid] : 0.f; cb1[tid] = (tid < 100) ? A.cmb1[tid] : 0.f; }
  if (tid < 64)  { vb2[tid] = A.vmb2[tid]; cb2[tid] = A.cmb2[tid]; vac[tid] = 0.f; }
  vbs[tid] = A.vbih[tid] + A.vbhh[tid];
  cbs[tid] = A.cbih[tid] + A.cbhh[tid];
  for (int i = tid; i < 1024; i += 256) { W1v[i] = A.voW1[i]; chl[i] = A.chInit[bb * 1024 + i]; ccl[i] = 0.f; }
  if (tid < 16) { b1v[tid] = A.vob1[tid]; W2v[tid] = A.voW2[tid]; }
  const u64 diagbits = A.diagBits[bb * 32 + (rb >> 6)];
  __syncthreads();

  // c_msg MLP (on current chl) + cm_sum + vertex-gate-const. Redundant per block.
  auto cmsgPhase = [&]() {
    for (int i = tid; i < 1024; i += 256) { int c = i >> 6, kk = i & 63; AtileU[c * 136 + kk] = f2b(chl[i]); }
    __syncthreads();
    floatx4 m1a = zf, m1b = zf;
#pragma unroll
    for (int ks = 0; ks < 2; ++ks) {
      short8 af = *(const short8*)(AtileU + l15 * 136 + ks * 32 + q * 8);
      short8 b0 = *(const short8*)(A.cw1 + (size_t)((w * 16 + l15) * 64 + ks * 32 + q * 8));
      m1a = __builtin_amdgcn_mfma_f32_16x16x32_bf16(af, b0, m1a, 0, 0, 0);
      if (w < 3) {
        short8 b1 = *(const short8*)(A.cw1 + (size_t)(((w + 4) * 16 + l15) * 64 + ks * 32 + q * 8));
        m1b = __builtin_amdgcn_mfma_f32_16x16x32_bf16(af, b1, m1b, 0, 0, 0);
      }
    }
#pragma unroll
    for (int reg = 0; reg < 4; ++reg) {
      float hv = m1a[reg] + cb1[w * 16 + l15];
      HtileU[(q * 4 + reg) * 136 + w * 16 + l15] = f2b(hv > 0.f ? hv : 0.f);
    }
    if (w < 3) {
#pragma unroll
      for (int reg = 0; reg < 4; ++reg) {
        float hv = m1b[reg] + cb1[(w + 4) * 16 + l15];
        HtileU[(q * 4 + reg) * 136 + (w + 4) * 16 + l15] = f2b(hv > 0.f ? hv : 0.f);
      }
    }
    // zero cols 112..127 of the 16 used rows (K padding for the W2 GEMM)
    if (tid < 128) {
      int r = tid >> 3, c = 112 + (tid & 7) * 2;
      HtileU[r * 136 + c] = 0; HtileU[r * 136 + c + 1] = 0;
    }
    __syncthreads();
    floatx4 m2 = zf;
#pragma unroll
    for (int ks = 0; ks < 4; ++ks) {
      short8 af = *(const short8*)(HtileU + l15 * 136 + ks * 32 + q * 8);
      short8 bv = *(const short8*)(A.cw2 + (size_t)((w * 16 + l15) * 128 + ks * 32 + q * 8));
      m2 = __builtin_amdgcn_mfma_f32_16x16x32_bf16(af, bv, m2, 0, 0, 0);
    }
    float s2 = 0.f;
#pragma unroll
    for (int reg = 0; reg < 4; ++reg) {
      int c = q * 4 + reg;
      float v = m2[reg] + cb2[w * 16 + l15];
      v = v > 0.f ? v : 0.f;
      if (c < ncolv) s2 += v;
    }
    s2 += __shfl_xor(s2, 16);
    s2 += __shfl_xor(s2, 32);
    if (q == 0) cms[w * 16 + l15] = s2;
    __syncthreads();
    {
      float dot = 0.f;
      const float* wr = A.vWih + tid * 128 + 64;    // right half of v_Wih (cm_sum input)
#pragma unroll
      for (int k2 = 0; k2 < 64; ++k2) dot += cms[k2] * wr[k2];
      gc[tid] = dot + vbs[tid];
    }
    __syncthreads();
  };

  float vc[4][4] = {};          // vertex cell state (fp32, regs)
  u16 hreg[16];                 // own rows' h_prev, lane = d
  {
    u16 h0 = A.vhbuf[(size_t)(bb * 64 + lane) * 2048 + rb];   // v_init[d]
#pragma unroll
    for (int r = 0; r < 16; ++r) hreg[r] = h0;
  }

  // chunk prefetch register sets (8 x u64 = 64 B/thread each)
  u64 R0[8], R1[8];
  auto issue8 = [&](u64 (&Rs)[8], const u16* src, int c) {
#pragma unroll
    for (int i = 0; i < 8; ++i) {
      int f = i * 256 + tid, d = f >> 5, j4 = f & 31;
      Rs[i] = l_agent_u64((const u64*)(src + (size_t)d * 2048 + c * 128 + j4 * 4));
    }
  };
  auto stage8 = [&](const u64 (&Rs)[8], u16* buf) {
#pragma unroll
    for (int i = 0; i < 8; ++i) {
      int f = i * 256 + tid, d = f >> 5, j4 = f & 31;
      *(u64*)(buf + d * 136 + j4 * 4) = Rs[i];
    }
  };

  // prefetch chunks 0/1 of step 0 (hidden under cmsgPhase)
  {
    const u16* v0 = A.vhbuf + (size_t)bb * 64 * 2048;
    issue8(R0, v0, 0);
    issue8(R1, v0, 1);
  }

  cmsgPhase();                  // prologue: gate const from ch_init
  unsigned ep = 0;

  const u64* arow = A.Abits + ((size_t)bb * 2048 + rb + w * 16 + l15) * 32;

  for (int t = 0; t < Tk; ++t) {
    const u16* vtr = A.vhbuf + (size_t)(t & 1) * SLOT + (size_t)bb * 64 * 2048;
    u16* vtw = A.vhbuf + (size_t)((t & 1) ^ 1) * SLOT + (size_t)bb * 64 * 2048;

    // ================= a1: Avh = (Mvv+I) @ vh, pipelined bit-MFMA over 16 chunks =================
    floatx4 acc4[4];
#pragma unroll
    for (int nt = 0; nt < 4; ++nt) acc4[nt] = zf;

    auto mfmaChunk = [&](const u16* buf, u64 w0, u64 w1) {
#pragma unroll
      for (int ks = 0; ks < 4; ++ks) {
        unsigned byte = (unsigned)(((ks & 2) ? w1 : w0) >> ((ks & 1) * 32 + q * 8)) & 0xFFu;
        short8 af;
#pragma unroll
        for (int j = 0; j < 8; ++j) af[j] = (short)(((byte >> j) & 1u) ? 0x3F80 : 0);
#pragma unroll
        for (int nt = 0; nt < 4; ++nt) {
          short8 bv = *(const short8*)(buf + (nt * 16 + l15) * 136 + ks * 32 + q * 8);
          acc4[nt] = __builtin_amdgcn_mfma_f32_16x16x32_bf16(af, bv, acc4[nt], 0, 0, 0);
        }
      }
    };

    // prologue: R0/R1 already hold chunks 0/1 (issued before loop / after last gridbar)
    stage8(R0, AtileU);          // waits only R0's own loads (R1 stays in flight)
    issue8(R0, vtr, 2);
    barrier_nodrain();

    for (int cc = 0; cc < 16; cc += 2) {
      // ---- even chunk cc (buf A); stage cc+1 -> H; refill R1 <- cc+3
      {
        u64 w0 = arow[cc * 2], w1 = arow[cc * 2 + 1];
        stage8(R1, HtileU);
        if (cc + 3 < 16) issue8(R1, vtr, cc + 3);
        mfmaChunk(AtileU, w0, w1);
        barrier_nodrain();
      }
      // ---- odd chunk cc+1 (buf H); stage cc+2 -> A; refill R0 <- cc+4
      {
        u64 w0 = arow[(cc + 1) * 2], w1 = arow[(cc + 1) * 2 + 1];
        if (cc + 2 < 16) {
          stage8(R0, AtileU);
          if (cc + 4 < 16) issue8(R0, vtr, cc + 4);
        }
        mfmaChunk(HtileU, w0, w1);
        if (cc + 2 < 16) barrier_nodrain();
      }
    }
    __syncthreads();  // full drain; A/H tiles free for reuse

    // write h_prev into A-tile cols 64..127 (lane = d, own rows — wave-local)
#pragma unroll
    for (int r = 0; r < 16; ++r) AtileU[(w * 16 + r) * 136 + 64 + lane] = hreg[r];
    // diag extra add (+1 more copy of h_prev where Mvv[r][r]=1), then write Avh cols 0..63
#pragma unroll
    for (int nt = 0; nt < 4; ++nt) {
#pragma unroll
      for (int reg = 0; reg < 4; ++reg) {
        int m = w * 16 + q * 4 + reg;
        float fl = (float)((diagbits >> m) & 1ull);
        float hp = b2f(AtileU[m * 136 + 64 + nt * 16 + l15]);
        AtileU[m * 136 + nt * 16 + l15] = f2b(acc4[nt][reg] + fl * hp);
      }
    }

    // ---- a2: gates = [Avh|vh] @ Wcat^T  (wave-local reads of own rows)
    floatx4 acc[16];
#pragma unroll
    for (int nt = 0; nt < 16; ++nt) acc[nt] = zf;
#pragma unroll
    for (int ks = 0; ks < 4; ++ks) {
      short8 af = *(const short8*)(AtileU + (w * 16 + l15) * 136 + ks * 32 + q * 8);
#pragma unroll
      for (int nt = 0; nt < 16; ++nt) {
        short8 bv = *(const short8*)(WcatU + (nt * 16 + l15) * 136 + ks * 32 + q * 8);
        acc[nt] = __builtin_amdgcn_mfma_f32_16x16x32_bf16(af, bv, acc[nt], 0, 0, 0);
      }
    }

    // ---- a3/a4: LSTM pointwise; h -> A-tile cols 0..63
#pragma unroll
    for (int u = 0; u < 4; ++u) {
      const int d2 = u * 16 + l15;
      const float gi = gc[d2], gf2 = gc[64 + d2], gg = gc[128 + d2], go = gc[192 + d2];
#pragma unroll
      for (int reg = 0; reg < 4; ++reg) {
        float iv = acc[u][reg] + gi;
        float fv = acc[u + 4][reg] + gf2;
        float gv = acc[u + 8][reg] + gg;
        float ov = acc[u + 12][reg] + go;
        float cn = sigf(fv) * vc[u][reg] + sigf(iv) * tanhf_(gv);
        vc[u][reg] = cn;
        AtileU[(w * 16 + q * 4 + reg) * 136 + d2] = f2b(sigf(ov) * tanhf_(cn));
      }
    }
    // snapshot own h for next step (wave-local LDS, ordered within wave)
#pragma unroll
    for (int r = 0; r < 16; ++r) hreg[r] = AtileU[(w * 16 + r) * 136 + lane];

    // ---- a5: v_msg hidden = relu(h @ W1^T + b1)  (wave-local)
    floatx4 h1[7];
#pragma unroll
    for (int nt = 0; nt < 7; ++nt) h1[nt] = zf;
#pragma unroll
    for (int ks = 0; ks < 2; ++ks) {
      short8 af = *(const short8*)(AtileU + (w * 16 + l15) * 136 + ks * 32 + q * 8);
#pragma unroll
      for (int nt = 0; nt < 7; ++nt) {
        short8 bv = *(const short8*)(vW1U + (nt * 16 + l15) * 72 + ks * 32 + q * 8);
        h1[nt] = __builtin_amdgcn_mfma_f32_16x16x32_bf16(af, bv, h1[nt], 0, 0, 0);
      }
    }
#pragma unroll
    for (int nt = 0; nt < 7; ++nt) {
      float bb1 = vb1[nt * 16 + l15];
#pragma unroll
      for (int reg = 0; reg < 4; ++reg) {
        float hv = h1[nt][reg] + bb1;
        HtileU[(w * 16 + q * 4 + reg) * 136 + nt * 16 + l15] = f2b(hv > 0.f ? hv : 0.f);
      }
    }
    // zero K-padding cols 112..127 of own rows
#pragma unroll
    for (int r = 0; r < 4; ++r) {
      int rr = w * 16 + q * 4 + r;
      HtileU[rr * 136 + 112 + l15] = 0;
    }

    // ---- a6: v_msg = relu(hidden @ W2^T + b2); reduce over rows
    floatx4 vm[4];
#pragma unroll
    for (int nt = 0; nt < 4; ++nt) vm[nt] = zf;
#pragma unroll
    for (int ks = 0; ks < 4; ++ks) {
      short8 af = *(const short8*)(HtileU + (w * 16 + l15) * 136 + ks * 32 + q * 8);
#pragma unroll
      for (int nt = 0; nt < 4; ++nt) {
        short8 bv = *(const short8*)(vW2U + (nt * 16 + l15) * 136 + ks * 32 + q * 8);
        vm[nt] = __builtin_amdgcn_mfma_f32_16x16x32_bf16(af, bv, vm[nt], 0, 0, 0);
      }
    }
#pragma unroll
    for (int u = 0; u < 4; ++u) {
      float bb2 = vb2[u * 16 + l15];
      float s = 0.f;
#pragma unroll
      for (int reg = 0; reg < 4; ++reg) { float v = vm[u][reg] + bb2; s += (v > 0.f ? v : 0.f); }
      s += __shfl_xor(s, 16);
      s += __shfl_xor(s, 32);
      if (q == 0) atomicAdd(&vac[u * 16 + l15], s);
    }
    __syncthreads();   // all waves' LSTM h in A-tile + vac complete

    // ---- publish: block partial (agent WT) + vh_new transposed [d][n] (agent WT)
    if (tid < 64) s_agent_f32(&A.partial[(size_t)((t & 1) * GBLK + blockIdx.x) * 64 + tid], vac[tid]);
#pragma unroll
    for (int ii = 0; ii < 4; ++ii) {
      int u = tid + ii * 256;            // 0..1023
      int d = u >> 4, r4 = (u & 15) * 4;
      u64 val = 0;
#pragma unroll
      for (int j = 0; j < 4; ++j) val |= ((u64)AtileU[(r4 + j) * 136 + d]) << (16 * j);
      s_agent_u64((u64*)(vtw + (size_t)d * 2048 + rb + r4), val);
    }
    __syncthreads();
    if (tid < 64) vac[tid] = 0.f;

    gridbar(A.bar, (++ep) * GBLK);

    if (t < Tk - 1) {
      // prefetch chunks 0/1 of next step NOW; color phase hides the latency
      issue8(R0, vtw, 0);
      issue8(R1, vtw, 1);

      // ---- color phase (redundant per block, local ch/cc) ----
      if (tid < 64) {
        float s = 0.f;
        const float* pp = A.partial + (size_t)((t & 1) * GBLK) * 64;
        for (int i2 = 0; i2 < 32; ++i2) s += l_agent_f32(&pp[(i2 * 8 + bb) * 64 + tid]);
        vms[tid] = s;
      }
      __syncthreads();
      for (int i2 = tid; i2 < 16 * 128; i2 += 256) {
        int c = i2 >> 7, kk = i2 & 127;
        float v = (kk < 64) ? ((c < ncolv) ? vms[kk] : 0.f) : chl[c * 64 + (kk - 64)];
        AtileU[c * 136 + kk] = f2b(v);
      }
      __syncthreads();
      floatx4 cacc[4];
#pragma unroll
      for (int j = 0; j < 4; ++j) cacc[j] = zf;
#pragma unroll
      for (int ks = 0; ks < 4; ++ks) {
        short8 af = *(const short8*)(AtileU + l15 * 136 + ks * 32 + q * 8);
#pragma unroll
        for (int j = 0; j < 4; ++j) {
          short8 bv = *(const short8*)(A.cwcat + (size_t)(((w * 4 + j) * 16 + l15) * 128 + ks * 32 + q * 8));
          cacc[j] = __builtin_amdgcn_mfma_f32_16x16x32_bf16(af, bv, cacc[j], 0, 0, 0);
        }
      }
      __syncthreads();
      float* cgp = (float*)(smem + OFF_AT);   // fp32 overlay for gate exchange
#pragma unroll
      for (int j = 0; j < 4; ++j)
#pragma unroll
        for (int reg = 0; reg < 4; ++reg)
          cgp[(q * 4 + reg) * 260 + (w * 4 + j) * 16 + l15] = cacc[j][reg];
      __syncthreads();
      for (int i2 = tid; i2 < 1024; i2 += 256) {
        int c = i2 >> 6, d2 = i2 & 63;
        float iv = cgp[c * 260 + d2] + cbs[d2];
        float fv = cgp[c * 260 + 64 + d2] + cbs[64 + d2];
        float gv = cgp[c * 260 + 128 + d2] + cbs[128 + d2];
        float ov = cgp[c * 260 + 192 + d2] + cbs[192 + d2];
        float cn = sigf(fv) * ccl[i2] + sigf(iv) * tanhf_(gv);
        ccl[i2] = cn;
        chl[i2] = sigf(ov) * tanhf_(cn);
      }
      __syncthreads();
      cmsgPhase();   // next step's gate const
    }
  }

  // ---- vote: h of own 64 rows is in A-tile cols 0..63 ----
  {
    int r = tid >> 2, p = tid & 3;
    float hj[4] = {0.f, 0.f, 0.f, 0.f};
    for (int d2 = 0; d2 < 64; ++d2) {
      float hv = b2f(AtileU[r * 136 + d2]);
#pragma unroll
      for (int jj = 0; jj < 4; ++jj) hj[jj] += hv * W1v[(p * 4 + jj) * 64 + d2];
    }
    float pv = 0.f;
#pragma unroll
    for (int jj = 0; jj < 4; ++jj) pv += sigf(hj[jj] + b1v[p * 4 + jj]) * W2v[p * 4 + jj];
    vot[tid] = pv;
  }
  __syncthreads();
  if (tid < 64) {
    float vr = vot[tid * 4] + vot[tid * 4 + 1] + vot[tid * 4 + 2] + vot[tid * 4 + 3] + A.vob2[0];
    vr += __shfl_xor(vr, 1);
    vr += __shfl_xor(vr, 2);
    vr += __shfl_xor(vr, 4);
    vr += __shfl_xor(vr, 8);
    vr += __shfl_xor(vr, 16);
    vr += __shfl_xor(vr, 32);
    if (tid == 0) atomicAdd(&A.voteAcc[bb], vr);
  }
  gridbar(A.bar, (++ep) * GBLK);
  if (blockIdx.x < 8 && tid == 0) {
    float m = l_agent_f32(&A.voteAcc[blockIdx.x]) * (1.f / 2048.f);
    A.out[blockIdx.x] = 1.f / (1.f + __expf(-m));
  }
}

// ---------- host ----------
extern "C" void kernel_launch(void* const* d_in, const int* in_sizes, int n_in,
                              void* d_out, int out_size, void* d_ws, size_t ws_size,
                              hipStream_t stream) {
  (void)in_sizes; (void)n_in; (void)out_size; (void)ws_size;
  const float* Mvv    = (const float*)d_in[0];
  const float* chInit = (const float*)d_in[1];
  const float* vInit  = (const float*)d_in[2];
  const float* vWih   = (const float*)d_in[3];
  const float* vWhh   = (const float*)d_in[4];
  const float* vbih   = (const float*)d_in[5];
  const float* vbhh   = (const float*)d_in[6];
  const float* cWih   = (const float*)d_in[7];
  const float* cWhh   = (const float*)d_in[8];
  const float* cbih   = (const float*)d_in[9];
  const float* cbhh   = (const float*)d_in[10];
  const float* cm1    = (const float*)d_in[11];
  const float* cmb1   = (const float*)d_in[12];
  const float* cm2    = (const float*)d_in[13];
  const float* cmb2   = (const float*)d_in[14];
  const float* vm1    = (const float*)d_in[15];
  const float* vmb1   = (const float*)d_in[16];
  const float* vm2    = (const float*)d_in[17];
  const float* vmb2   = (const float*)d_in[18];
  const float* voW1   = (const float*)d_in[19];
  const float* vob1   = (const float*)d_in[20];
  const float* voW2   = (const float*)d_in[21];
  const float* vob2   = (const float*)d_in[22];
  const int*   ncol   = (const int*)d_in[23];

  char* wsb = (char*)d_ws;
  size_t off = 0;
  auto wsAlloc = [&](size_t bytes) -> char* {
    char* p = wsb + off;
    off = (off + bytes + 255) & ~(size_t)255;
    return p;
  };
  unsigned* bar   = (unsigned*)wsAlloc(256);
  float* voteAcc  = (float*)((char*)bar + 64);
  u16* vhb        = (u16*)wsAlloc((size_t)2 * SLOT * 2);               // 4 MB
  u64* Abits      = (u64*)wsAlloc((size_t)Bk * Nk * 32 * 8);           // 4 MB
  u64* diagBits   = (u64*)wsAlloc((size_t)Bk * 32 * 8);                // 2 KB
  float* partial  = (float*)wsAlloc((size_t)2 * GBLK * 64 * 4);        // 128 KB
  u16* wcat       = (u16*)wsAlloc(256 * 128 * 2);
  u16* cwcat      = (u16*)wsAlloc(256 * 128 * 2);
  u16* vw1        = (u16*)wsAlloc(112 * 64 * 2);
  u16* vw2        = (u16*)wsAlloc(64 * 128 * 2);
  u16* cw1        = (u16*)wsAlloc(112 * 64 * 2);
  u16* cw2        = (u16*)wsAlloc(64 * 128 * 2);

  k_init_w<<<1, 256, 0, stream>>>(vWih, vWhh, cWih, cWhh, vm1, vm2, cm1, cm2,
                                  wcat, cwcat, vw1, vw2, cw1, cw2, bar, voteAcc, diagBits);
  k_init_vt<<<256, 256, 0, stream>>>(vInit, vhb);
  k_bits<<<Bk * Nk / 4, 256, 0, stream>>>(Mvv, Abits, diagBits);

  (void)hipFuncSetAttribute((const void*)k_persist,
                            hipFuncAttributeMaxDynamicSharedMemorySize, LDS_TOTAL);
  PArgs pa;
  pa.vWih = vWih; pa.chInit = chInit;
  pa.vbih = vbih; pa.vbhh = vbhh; pa.cbih = cbih; pa.cbhh = cbhh;
  pa.vmb1 = vmb1; pa.vmb2 = vmb2; pa.cmb1 = cmb1; pa.cmb2 = cmb2;
  pa.voW1 = voW1; pa.vob1 = vob1; pa.voW2 = voW2; pa.vob2 = vob2;
  pa.ncolors = ncol;
  pa.vhbuf = vhb; pa.Abits = Abits; pa.diagBits = diagBits; pa.partial = partial;
  pa.wcat = wcat; pa.cwcat = cwcat; pa.vw1 = vw1; pa.vw2 = vw2; pa.cw1 = cw1; pa.cw2 = cw2;
  pa.bar = bar; pa.voteAcc = voteAcc; pa.out = (float*)d_out;
  k_persist<<<GBLK, 256, LDS_TOTAL, stream>>>(pa);
}

// Round 5
// 1663.009 us; speedup vs baseline: 3.6489x; 1.0780x over previous
//
#include <hip/hip_runtime.h>

#define Bk 8
#define Nk 2048
#define Ck 16
#define Dk 64
#define Tk 32
#define GBLK 256
#define SLOT (Bk * 64 * 2048)   // ushorts per vh_t slot

typedef __attribute__((ext_vector_type(8))) short short8;
typedef __attribute__((ext_vector_type(4))) float floatx4;
typedef __attribute__((ext_vector_type(4))) unsigned uint4v;
typedef unsigned long long u64;
typedef unsigned short u16;

// ---------- LDS layout (dynamic, one block/CU) ----------
#define OFF_WCAT 0           // [256][136] bf16  vertex gate weights (Wih_left|Whh)
#define OFF_VW1  69632       // [112][72]  bf16  vmsg W1 (padded 100->112)
#define OFF_VW2  85760       // [64][136]  bf16  vmsg W2 (K padded 100->128, zeros)
#define OFF_AT   103168      // [64][136]  bf16  A-tile / chunk buf 0
#define OFF_HT   120576      // [64][136]  bf16  H-tile / chunk buf 1
#define OFF_CH   137984      // [16][64] f32 ch (block-local color state)
#define OFF_CC   142080      // [16][64] f32 cc
#define OFF_GC   146176      // [256] f32 gate const (cm term + biases)
#define OFF_VBS  147200      // [256] f32 v_bih+v_bhh
#define OFF_CBS  148224      // [256] f32 c_bih+c_bhh
#define OFF_VB1  149248      // [112] f32
#define OFF_VB2  149760      // [64]  f32
#define OFF_CB1  150016      // [112] f32
#define OFF_CB2  150528      // [64]  f32
#define OFF_W1V  150784      // [16][64] f32 vote W1
#define OFF_B1V  154880      // [16] f32
#define OFF_W2V  154944      // [16] f32
#define OFF_VAC  155008      // [64] f32 vmsg accum (LDS atomics)
#define OFF_VMS  155264      // [64] f32 vmsg_sum (batch)
#define OFF_CMS  155520      // [64] f32 cm_sum
#define OFF_VOT  155776      // [256] f32 vote scratch
#define LDS_TOTAL 156800

__device__ __forceinline__ float b2f(u16 u) {
  return __uint_as_float(((unsigned)u) << 16);
}
__device__ __forceinline__ u16 f2b(float f) {
  unsigned u = __float_as_uint(f);
  unsigned r = (u + 0x7FFFu + ((u >> 16) & 1u)) >> 16;
  return (u16)r;
}
__device__ __forceinline__ float sigf(float x) { return 1.0f / (1.0f + __expf(-x)); }
__device__ __forceinline__ float tanhf_(float x) { return 2.0f / (1.0f + __expf(-2.0f * x)) - 1.0f; }

// ---- system-scope (MALL-coherent) streaming loads/stores via inline asm ----
// sc0 sc1 on loads: bypass L1+L2, read at MALL (coherent point for WT stores).
// sc0 sc1 on stores: write through to MALL. Full-BW path, NOT the atomic path.
__device__ __forceinline__ void ld_sys_b128(uint4v& dst, const void* p) {
  asm volatile("global_load_dwordx4 %0, %1, off sc0 sc1" : "=v"(dst) : "v"(p) : "memory");
}
__device__ __forceinline__ void ld_b128(uint4v& dst, const void* p) {
  asm volatile("global_load_dwordx4 %0, %1, off" : "=v"(dst) : "v"(p) : "memory");
}
__device__ __forceinline__ void st_sys_b128(void* p, uint4v v) {
  asm volatile("global_store_dwordx4 %0, %1, off sc0 sc1" :: "v"(p), "v"(v) : "memory");
}
#define WAITVM(n) asm volatile("s_waitcnt vmcnt(" #n ")" ::: "memory")
__device__ __forceinline__ void barrier_lgkm() {
  asm volatile("s_waitcnt lgkmcnt(0)\n\ts_barrier" ::: "memory");
}

// agent-scope atomics for the small cross-block scalars (partials / votes / bar)
__device__ __forceinline__ void s_agent_f32(float* p, float v) {
  __hip_atomic_store(p, v, __ATOMIC_RELAXED, __HIP_MEMORY_SCOPE_AGENT);
}
__device__ __forceinline__ float l_agent_f32(const float* p) {
  return __hip_atomic_load(p, __ATOMIC_RELAXED, __HIP_MEMORY_SCOPE_AGENT);
}

// ---------- one-time init kernels ----------
__global__ void k_init_w(const float* vWih, const float* vWhh, const float* cWih, const float* cWhh,
                         const float* vm1, const float* vm2, const float* cm1, const float* cm2,
                         u16* wcat, u16* cwcat, u16* vw1, u16* vw2, u16* cw1, u16* cw2,
                         unsigned* bar, float* voteAcc, u64* diagBits) {
  const int tid = threadIdx.x;
  for (int i = tid; i < 256 * 128; i += 256) {
    int g = i >> 7, k = i & 127;
    wcat[i]  = f2b(k < 64 ? vWih[g * 128 + k] : vWhh[g * 64 + (k - 64)]);
    cwcat[i] = f2b(k < 64 ? cWih[g * 64 + k]  : cWhh[g * 64 + (k - 64)]);
  }
  for (int i = tid; i < 112 * 64; i += 256) {
    int j = i >> 6, k = i & 63;
    vw1[i] = f2b(j < 100 ? vm1[j * 64 + k] : 0.f);
    cw1[i] = f2b(j < 100 ? cm1[j * 64 + k] : 0.f);
  }
  for (int i = tid; i < 64 * 128; i += 256) {
    int d = i >> 7, k = i & 127;
    vw2[i] = f2b(k < 100 ? vm2[d * 100 + k] : 0.f);
    cw2[i] = f2b(k < 100 ? cm2[d * 100 + k] : 0.f);
  }
  if (tid == 0) *bar = 0u;
  if (tid < 8) voteAcc[tid] = 0.f;
  if (tid < 256) diagBits[tid] = 0ull;   // [B][32]
}

// vh_t slot 0 = v_init broadcast, layout [b][d][n]
__global__ void k_init_vt(const float* vInit, u16* vt0) {
  for (int i = blockIdx.x * blockDim.x + threadIdx.x; i < SLOT; i += gridDim.x * blockDim.x) {
    int d = (i >> 11) & 63;
    vt0[i] = f2b(vInit[d]);
  }
}

// bit-pack A = Mvv(+I); diag flag (Mvv[r][r]) separately. One wave per row.
__global__ void k_bits(const float* Mvv, u64* Abits, u64* diagBits) {
  const int lane = threadIdx.x & 63;
  const int wid = blockIdx.x * 4 + (threadIdx.x >> 6);   // global row in [0, B*N)
  const int b = wid >> 11, n = wid & 2047;
  const float* row = Mvv + (size_t)wid * Nk;
  u64* dst = Abits + (size_t)wid * 32;
  for (int w64 = 0; w64 < 32; ++w64) {
    float v = row[w64 * 64 + lane];
    u64 m = __ballot(v != 0.0f);
    if (lane == 0) {
      if (w64 == (n >> 6)) {
        if ((m >> (n & 63)) & 1ull)   // Mvv has a self edge -> diag weight 2
          atomicOr(diagBits + b * 32 + (n >> 6), 1ull << (n & 63));
        m |= 1ull << (n & 63);        // +I self loop
      }
      dst[w64] = m;
    }
  }
}

// ---------- persistent kernel ----------
struct PArgs {
  const float *vWih, *chInit;
  const float *vbih, *vbhh, *cbih, *cbhh;
  const float *vmb1, *vmb2, *cmb1, *cmb2;
  const float *voW1, *vob1, *voW2, *vob2;
  const int* ncolors;
  u16* vhbuf;                    // [2][B][64][2048] bf16, transposed layout
  const u64* Abits;              // [B][2048][32]
  const u64* diagBits;           // [B][32]
  float* partial;                // [2][GBLK][64]
  const u16 *wcat, *cwcat, *vw1, *vw2, *cw1, *cw2;
  unsigned* bar;
  float* voteAcc;
  float* out;
};

__device__ __forceinline__ void gridbar(unsigned* bar, unsigned target) {
  WAITVM(0);         // drain asm sys-stores (compiler can't see them) before flagging
  __syncthreads();
  if (threadIdx.x == 0) {
    atomicAdd(bar, 1u);
    int guard = 0;
    while (__hip_atomic_load(bar, __ATOMIC_RELAXED, __HIP_MEMORY_SCOPE_AGENT) < target) {
      __builtin_amdgcn_s_sleep(2);
      if (++guard > (1 << 24)) break;
    }
  }
  __syncthreads();
}

__global__ void __launch_bounds__(256, 1) k_persist(PArgs A) {
  extern __shared__ char smem[];
  u16* WcatU  = (u16*)(smem + OFF_WCAT);
  u16* vW1U   = (u16*)(smem + OFF_VW1);
  u16* vW2U   = (u16*)(smem + OFF_VW2);
  u16* AtileU = (u16*)(smem + OFF_AT);
  u16* HtileU = (u16*)(smem + OFF_HT);
  float* chl = (float*)(smem + OFF_CH);
  float* ccl = (float*)(smem + OFF_CC);
  float* gc  = (float*)(smem + OFF_GC);
  float* vbs = (float*)(smem + OFF_VBS);
  float* cbs = (float*)(smem + OFF_CBS);
  float* vb1 = (float*)(smem + OFF_VB1);
  float* vb2 = (float*)(smem + OFF_VB2);
  float* cb1 = (float*)(smem + OFF_CB1);
  float* cb2 = (float*)(smem + OFF_CB2);
  float* W1v = (float*)(smem + OFF_W1V);
  float* b1v = (float*)(smem + OFF_B1V);
  float* W2v = (float*)(smem + OFF_W2V);
  float* vac = (float*)(smem + OFF_VAC);
  float* vms = (float*)(smem + OFF_VMS);
  float* cms = (float*)(smem + OFF_CMS);
  float* vot = (float*)(smem + OFF_VOT);

  const int tid = threadIdx.x;
  const int lane = tid & 63;
  const int w = tid >> 6;          // wave id 0..3 == M-tile
  const int q = lane >> 4;         // quad
  const int l15 = lane & 15;
  const int bb = blockIdx.x & 7;             // batch
  const int rb = (blockIdx.x >> 3) * 64;     // row base within batch
  const int ncolv = A.ncolors[bb];
  const floatx4 zf = {0.f, 0.f, 0.f, 0.f};

  // ---- stage weights/biases/state into LDS (once) ----
  for (int i = tid; i < 256 * 128; i += 256) { int g = i >> 7, k = i & 127; WcatU[g * 136 + k] = A.wcat[i]; }
  for (int i = tid; i < 112 * 64; i += 256)  { int j = i >> 6, k = i & 63;  vW1U[j * 72 + k]  = A.vw1[i]; }
  for (int i = tid; i < 64 * 128; i += 256)  { int d = i >> 7, k = i & 127; vW2U[d * 136 + k] = A.vw2[i]; }
  if (tid < 112) { vb1[tid] = (tid < 100) ? A.vmb1[tid] : 0.f; cb1[tid] = (tid < 100) ? A.cmb1[tid] : 0.f; }
  if (tid < 64)  { vb2[tid] = A.vmb2[tid]; cb2[tid] = A.cmb2[tid]; vac[tid] = 0.f; }
  vbs[tid] = A.vbih[tid] + A.vbhh[tid];
  cbs[tid] = A.cbih[tid] + A.cbhh[tid];
  for (int i = tid; i < 1024; i += 256) { W1v[i] = A.voW1[i]; chl[i] = A.chInit[bb * 1024 + i]; ccl[i] = 0.f; }
  if (tid < 16) { b1v[tid] = A.vob1[tid]; W2v[tid] = A.voW2[tid]; }
  const u64 diagbits = A.diagBits[bb * 32 + (rb >> 6)];
  __syncthreads();

  // c_msg MLP (on current chl) + cm_sum + vertex-gate-const. Redundant per block.
  auto cmsgPhase = [&]() {
    for (int i = tid; i < 1024; i += 256) { int c = i >> 6, kk = i & 63; AtileU[c * 136 + kk] = f2b(chl[i]); }
    __syncthreads();
    floatx4 m1a = zf, m1b = zf;
#pragma unroll
    for (int ks = 0; ks < 2; ++ks) {
      short8 af = *(const short8*)(AtileU + l15 * 136 + ks * 32 + q * 8);
      short8 b0 = *(const short8*)(A.cw1 + (size_t)((w * 16 + l15) * 64 + ks * 32 + q * 8));
      m1a = __builtin_amdgcn_mfma_f32_16x16x32_bf16(af, b0, m1a, 0, 0, 0);
      if (w < 3) {
        short8 b1 = *(const short8*)(A.cw1 + (size_t)(((w + 4) * 16 + l15) * 64 + ks * 32 + q * 8));
        m1b = __builtin_amdgcn_mfma_f32_16x16x32_bf16(af, b1, m1b, 0, 0, 0);
      }
    }
#pragma unroll
    for (int reg = 0; reg < 4; ++reg) {
      float hv = m1a[reg] + cb1[w * 16 + l15];
      HtileU[(q * 4 + reg) * 136 + w * 16 + l15] = f2b(hv > 0.f ? hv : 0.f);
    }
    if (w < 3) {
#pragma unroll
      for (int reg = 0; reg < 4; ++reg) {
        float hv = m1b[reg] + cb1[(w + 4) * 16 + l15];
        HtileU[(q * 4 + reg) * 136 + (w + 4) * 16 + l15] = f2b(hv > 0.f ? hv : 0.f);
      }
    }
    // zero cols 112..127 of the 16 used rows (K padding for the W2 GEMM)
    if (tid < 128) {
      int r = tid >> 3, c = 112 + (tid & 7) * 2;
      HtileU[r * 136 + c] = 0; HtileU[r * 136 + c + 1] = 0;
    }
    __syncthreads();
    floatx4 m2 = zf;
#pragma unroll
    for (int ks = 0; ks < 4; ++ks) {
      short8 af = *(const short8*)(HtileU + l15 * 136 + ks * 32 + q * 8);
      short8 bv = *(const short8*)(A.cw2 + (size_t)((w * 16 + l15) * 128 + ks * 32 + q * 8));
      m2 = __builtin_amdgcn_mfma_f32_16x16x32_bf16(af, bv, m2, 0, 0, 0);
    }
    float s2 = 0.f;
#pragma unroll
    for (int reg = 0; reg < 4; ++reg) {
      int c = q * 4 + reg;
      float v = m2[reg] + cb2[w * 16 + l15];
      v = v > 0.f ? v : 0.f;
      if (c < ncolv) s2 += v;
    }
    s2 += __shfl_xor(s2, 16);
    s2 += __shfl_xor(s2, 32);
    if (q == 0) cms[w * 16 + l15] = s2;
    __syncthreads();
    {
      float dot = 0.f;
      const float* wr = A.vWih + tid * 128 + 64;    // right half of v_Wih (cm_sum input)
#pragma unroll
      for (int k2 = 0; k2 < 64; ++k2) dot += cms[k2] * wr[k2];
      gc[tid] = dot + vbs[tid];
    }
    __syncthreads();
  };

  float vc[4][4] = {};          // vertex cell state (fp32, regs)
  u16 hreg[16];                 // own rows' h_prev, lane = d
  {
    u16 h0 = A.vhbuf[(size_t)(bb * 64 + lane) * 2048 + rb];   // v_init[d]
#pragma unroll
    for (int r = 0; r < 16; ++r) hreg[r] = h0;
  }

  cmsgPhase();                  // prologue: gate const from ch_init
  unsigned ep = 0;

  const u64* arow = A.Abits + ((size_t)bb * 2048 + rb + w * 16 + l15) * 32;

  for (int t = 0; t < Tk; ++t) {
    const u16* vtr = A.vhbuf + (size_t)(t & 1) * SLOT + (size_t)bb * 64 * 2048;
    u16* vtw = A.vhbuf + (size_t)((t & 1) ^ 1) * SLOT + (size_t)bb * 64 * 2048;

    // ================= a1: Avh = (Mvv+I) @ vh, asm-pipelined bit-MFMA, 16 chunks =================
    floatx4 acc4[4];
#pragma unroll
    for (int nt = 0; nt < 4; ++nt) acc4[nt] = zf;

    uint4v D[2][4];     // data regs: group g -> D[g&1]
    uint4v Bts[4];      // bits regs: group g -> Bts[g&3]

    auto issueGroup = [&](int c, uint4v (&Ds)[4], uint4v& Bv) {
      ld_b128(Bv, (const char*)arow + (size_t)c * 16);       // A-bits, L2-cached
      const char* base = (const char*)vtr + (size_t)c * 256;
#pragma unroll
      for (int i = 0; i < 4; ++i) {
        int idx = i * 256 + tid, d = idx >> 4, j2 = idx & 15;
        ld_sys_b128(Ds[i], base + (size_t)d * 4096 + j2 * 16);
      }
    };
    auto stageGroup = [&](const uint4v (&Ds)[4], u16* buf) {
#pragma unroll
      for (int i = 0; i < 4; ++i) {
        int idx = i * 256 + tid, d = idx >> 4, j2 = idx & 15;
        *(uint4v*)((char*)buf + (size_t)d * 272 + j2 * 16) = Ds[i];
      }
    };
    auto mfmaChunk = [&](const u16* buf, u64 w0, u64 w1) {
#pragma unroll
      for (int ks = 0; ks < 4; ++ks) {
        unsigned byte = (unsigned)(((ks & 2) ? w1 : w0) >> ((ks & 1) * 32 + q * 8)) & 0xFFu;
        short8 af;
#pragma unroll
        for (int j = 0; j < 8; ++j) af[j] = (short)(((byte >> j) & 1u) ? 0x3F80 : 0);
#pragma unroll
        for (int nt = 0; nt < 4; ++nt) {
          short8 bv = *(const short8*)(buf + (nt * 16 + l15) * 136 + ks * 32 + q * 8);
          acc4[nt] = __builtin_amdgcn_mfma_f32_16x16x32_bf16(af, bv, acc4[nt], 0, 0, 0);
        }
      }
    };

    // prologue: groups 0,1 in flight; stage 0; keep depth 2 from then on
    issueGroup(0, D[0], Bts[0]);
    issueGroup(1, D[1], Bts[1]);
    WAITVM(5);                       // group 0 complete (group 1 in flight)
    stageGroup(D[0], AtileU);
    issueGroup(2, D[0], Bts[2]);
    barrier_lgkm();

#pragma unroll
    for (int c = 0; c < 16; ++c) {
      if (c < 14) { WAITVM(5); } else { WAITVM(0); }       // group c+1 data+bits ready
      if (c < 15) {
        stageGroup(D[(c + 1) & 1], ((c + 1) & 1) ? HtileU : AtileU);
        if (c + 3 < 16) issueGroup(c + 3, D[(c + 1) & 1], Bts[(c + 3) & 3]);
      }
      {
        const uint4v& Bv = Bts[c & 3];
        u64 w0 = ((u64)Bv[1] << 32) | Bv[0];
        u64 w1 = ((u64)Bv[3] << 32) | Bv[2];
        mfmaChunk((c & 1) ? HtileU : AtileU, w0, w1);
      }
      if (c < 15) barrier_lgkm();
    }
    __syncthreads();  // all chunk compute done; A/H tiles free

    // write h_prev into A-tile cols 64..127 (lane = d, own rows — wave-local)
#pragma unroll
    for (int r = 0; r < 16; ++r) AtileU[(w * 16 + r) * 136 + 64 + lane] = hreg[r];
    // diag extra add (+1 more copy of h_prev where Mvv[r][r]=1), then write Avh cols 0..63
#pragma unroll
    for (int nt = 0; nt < 4; ++nt) {
#pragma unroll
      for (int reg = 0; reg < 4; ++reg) {
        int m = w * 16 + q * 4 + reg;
        float fl = (float)((diagbits >> m) & 1ull);
        float hp = b2f(AtileU[m * 136 + 64 + nt * 16 + l15]);
        AtileU[m * 136 + nt * 16 + l15] = f2b(acc4[nt][reg] + fl * hp);
      }
    }

    // ---- a2: gates = [Avh|vh] @ Wcat^T  (wave-local reads of own rows)
    floatx4 acc[16];
#pragma unroll
    for (int nt = 0; nt < 16; ++nt) acc[nt] = zf;
#pragma unroll
    for (int ks = 0; ks < 4; ++ks) {
      short8 af = *(const short8*)(AtileU + (w * 16 + l15) * 136 + ks * 32 + q * 8);
#pragma unroll
      for (int nt = 0; nt < 16; ++nt) {
        short8 bv = *(const short8*)(WcatU + (nt * 16 + l15) * 136 + ks * 32 + q * 8);
        acc[nt] = __builtin_amdgcn_mfma_f32_16x16x32_bf16(af, bv, acc[nt], 0, 0, 0);
      }
    }

    // ---- a3/a4: LSTM pointwise; h -> A-tile cols 0..63
#pragma unroll
    for (int u = 0; u < 4; ++u) {
      const int d2 = u * 16 + l15;
      const float gi = gc[d2], gf2 = gc[64 + d2], gg = gc[128 + d2], go = gc[192 + d2];
#pragma unroll
      for (int reg = 0; reg < 4; ++reg) {
        float iv = acc[u][reg] + gi;
        float fv = acc[u + 4][reg] + gf2;
        float gv = acc[u + 8][reg] + gg;
        float ov = acc[u + 12][reg] + go;
        float cn = sigf(fv) * vc[u][reg] + sigf(iv) * tanhf_(gv);
        vc[u][reg] = cn;
        AtileU[(w * 16 + q * 4 + reg) * 136 + d2] = f2b(sigf(ov) * tanhf_(cn));
      }
    }
    // snapshot own h for next step (wave-local LDS, ordered within wave)
#pragma unroll
    for (int r = 0; r < 16; ++r) hreg[r] = AtileU[(w * 16 + r) * 136 + lane];

    // ---- a5: v_msg hidden = relu(h @ W1^T + b1)  (wave-local)
    floatx4 h1[7];
#pragma unroll
    for (int nt = 0; nt < 7; ++nt) h1[nt] = zf;
#pragma unroll
    for (int ks = 0; ks < 2; ++ks) {
      short8 af = *(const short8*)(AtileU + (w * 16 + l15) * 136 + ks * 32 + q * 8);
#pragma unroll
      for (int nt = 0; nt < 7; ++nt) {
        short8 bv = *(const short8*)(vW1U + (nt * 16 + l15) * 72 + ks * 32 + q * 8);
        h1[nt] = __builtin_amdgcn_mfma_f32_16x16x32_bf16(af, bv, h1[nt], 0, 0, 0);
      }
    }
#pragma unroll
    for (int nt = 0; nt < 7; ++nt) {
      float bb1 = vb1[nt * 16 + l15];
#pragma unroll
      for (int reg = 0; reg < 4; ++reg) {
        float hv = h1[nt][reg] + bb1;
        HtileU[(w * 16 + q * 4 + reg) * 136 + nt * 16 + l15] = f2b(hv > 0.f ? hv : 0.f);
      }
    }
    // zero K-padding cols 112..127 of own rows
#pragma unroll
    for (int r = 0; r < 4; ++r) {
      int rr = w * 16 + q * 4 + r;
      HtileU[rr * 136 + 112 + l15] = 0;
    }

    // ---- a6: v_msg = relu(hidden @ W2^T + b2); reduce over rows
    floatx4 vm[4];
#pragma unroll
    for (int nt = 0; nt < 4; ++nt) vm[nt] = zf;
#pragma unroll
    for (int ks = 0; ks < 4; ++ks) {
      short8 af = *(const short8*)(HtileU + (w * 16 + l15) * 136 + ks * 32 + q * 8);
#pragma unroll
      for (int nt = 0; nt < 4; ++nt) {
        short8 bv = *(const short8*)(vW2U + (nt * 16 + l15) * 136 + ks * 32 + q * 8);
        vm[nt] = __builtin_amdgcn_mfma_f32_16x16x32_bf16(af, bv, vm[nt], 0, 0, 0);
      }
    }
#pragma unroll
    for (int u = 0; u < 4; ++u) {
      float bb2 = vb2[u * 16 + l15];
      float s = 0.f;
#pragma unroll
      for (int reg = 0; reg < 4; ++reg) { float v = vm[u][reg] + bb2; s += (v > 0.f ? v : 0.f); }
      s += __shfl_xor(s, 16);
      s += __shfl_xor(s, 32);
      if (q == 0) atomicAdd(&vac[u * 16 + l15], s);
    }
    __syncthreads();   // all waves' LSTM h in A-tile + vac complete

    // ---- publish: block partial (agent WT) + vh_new transposed [d][n] (sys stores)
    if (tid < 64) s_agent_f32(&A.partial[(size_t)((t & 1) * GBLK + blockIdx.x) * 64 + tid], vac[tid]);
    {
      int d = tid >> 2, rr = (tid & 3) * 16;
      union { u16 s[8]; uint4v v; } p0, p1;
#pragma unroll
      for (int j = 0; j < 8; ++j) {
        p0.s[j] = AtileU[(rr + j) * 136 + d];
        p1.s[j] = AtileU[(rr + 8 + j) * 136 + d];
      }
      char* dst = (char*)(vtw + (size_t)d * 2048 + rb + rr);
      st_sys_b128(dst, p0.v);
      st_sys_b128(dst + 16, p1.v);
    }
    __syncthreads();
    if (tid < 64) vac[tid] = 0.f;

    gridbar(A.bar, (++ep) * GBLK);   // WAITVM(0) inside drains the sys stores

    if (t < Tk - 1) {
      // ---- color phase (redundant per block, local ch/cc) ----
      if (tid < 64) {
        float s = 0.f;
        const float* pp = A.partial + (size_t)((t & 1) * GBLK) * 64;
        for (int i2 = 0; i2 < 32; ++i2) s += l_agent_f32(&pp[(i2 * 8 + bb) * 64 + tid]);
        vms[tid] = s;
      }
      __syncthreads();
      for (int i2 = tid; i2 < 16 * 128; i2 += 256) {
        int c = i2 >> 7, kk = i2 & 127;
        float v = (kk < 64) ? ((c < ncolv) ? vms[kk] : 0.f) : chl[c * 64 + (kk - 64)];
        AtileU[c * 136 + kk] = f2b(v);
      }
      __syncthreads();
      floatx4 cacc[4];
#pragma unroll
      for (int j = 0; j < 4; ++j) cacc[j] = zf;
#pragma unroll
      for (int ks = 0; ks < 4; ++ks) {
        short8 af = *(const short8*)(AtileU + l15 * 136 + ks * 32 + q * 8);
#pragma unroll
        for (int j = 0; j < 4; ++j) {
          short8 bv = *(const short8*)(A.cwcat + (size_t)(((w * 4 + j) * 16 + l15) * 128 + ks * 32 + q * 8));
          cacc[j] = __builtin_amdgcn_mfma_f32_16x16x32_bf16(af, bv, cacc[j], 0, 0, 0);
        }
      }
      __syncthreads();
      float* cgp = (float*)(smem + OFF_AT);   // fp32 overlay for gate exchange
#pragma unroll
      for (int j = 0; j < 4; ++j)
#pragma unroll
        for (int reg = 0; reg < 4; ++reg)
          cgp[(q * 4 + reg) * 260 + (w * 4 + j) * 16 + l15] = cacc[j][reg];
      __syncthreads();
      for (int i2 = tid; i2 < 1024; i2 += 256) {
        int c = i2 >> 6, d2 = i2 & 63;
        float iv = cgp[c * 260 + d2] + cbs[d2];
        float fv = cgp[c * 260 + 64 + d2] + cbs[64 + d2];
        float gv = cgp[c * 260 + 128 + d2] + cbs[128 + d2];
        float ov = cgp[c * 260 + 192 + d2] + cbs[192 + d2];
        float cn = sigf(fv) * ccl[i2] + sigf(iv) * tanhf_(gv);
        ccl[i2] = cn;
        chl[i2] = sigf(ov) * tanhf_(cn);
      }
      __syncthreads();
      cmsgPhase();   // next step's gate const
    }
  }

  // ---- vote: h of own 64 rows is in A-tile cols 0..63 ----
  {
    int r = tid >> 2, p = tid & 3;
    float hj[4] = {0.f, 0.f, 0.f, 0.f};
    for (int d2 = 0; d2 < 64; ++d2) {
      float hv = b2f(AtileU[r * 136 + d2]);
#pragma unroll
      for (int jj = 0; jj < 4; ++jj) hj[jj] += hv * W1v[(p * 4 + jj) * 64 + d2];
    }
    float pv = 0.f;
#pragma unroll
    for (int jj = 0; jj < 4; ++jj) pv += sigf(hj[jj] + b1v[p * 4 + jj]) * W2v[p * 4 + jj];
    vot[tid] = pv;
  }
  __syncthreads();
  if (tid < 64) {
    float vr = vot[tid * 4] + vot[tid * 4 + 1] + vot[tid * 4 + 2] + vot[tid * 4 + 3] + A.vob2[0];
    vr += __shfl_xor(vr, 1);
    vr += __shfl_xor(vr, 2);
    vr += __shfl_xor(vr, 4);
    vr += __shfl_xor(vr, 8);
    vr += __shfl_xor(vr, 16);
    vr += __shfl_xor(vr, 32);
    if (tid == 0) atomicAdd(&A.voteAcc[bb], vr);
  }
  gridbar(A.bar, (++ep) * GBLK);
  if (blockIdx.x < 8 && tid == 0) {
    float m = l_agent_f32(&A.voteAcc[blockIdx.x]) * (1.f / 2048.f);
    A.out[blockIdx.x] = 1.f / (1.f + __expf(-m));
  }
}

// ---------- host ----------
extern "C" void kernel_launch(void* const* d_in, const int* in_sizes, int n_in,
                              void* d_out, int out_size, void* d_ws, size_t ws_size,
                              hipStream_t stream) {
  (void)in_sizes; (void)n_in; (void)out_size; (void)ws_size;
  const float* Mvv    = (const float*)d_in[0];
  const float* chInit = (const float*)d_in[1];
  const float* vInit  = (const float*)d_in[2];
  const float* vWih   = (const float*)d_in[3];
  const float* vWhh   = (const float*)d_in[4];
  const float* vbih   = (const float*)d_in[5];
  const float* vbhh   = (const float*)d_in[6];
  const float* cWih   = (const float*)d_in[7];
  const float* cWhh   = (const float*)d_in[8];
  const float* cbih   = (const float*)d_in[9];
  const float* cbhh   = (const float*)d_in[10];
  const float* cm1    = (const float*)d_in[11];
  const float* cmb1   = (const float*)d_in[12];
  const float* cm2    = (const float*)d_in[13];
  const float* cmb2   = (const float*)d_in[14];
  const float* vm1    = (const float*)d_in[15];
  const float* vmb1   = (const float*)d_in[16];
  const float* vm2    = (const float*)d_in[17];
  const float* vmb2   = (const float*)d_in[18];
  const float* voW1   = (const float*)d_in[19];
  const float* vob1   = (const float*)d_in[20];
  const float* voW2   = (const float*)d_in[21];
  const float* vob2   = (const float*)d_in[22];
  const int*   ncol   = (const int*)d_in[23];

  char* wsb = (char*)d_ws;
  size_t off = 0;
  auto wsAlloc = [&](size_t bytes) -> char* {
    char* p = wsb + off;
    off = (off + bytes + 255) & ~(size_t)255;
    return p;
  };
  unsigned* bar   = (unsigned*)wsAlloc(256);
  float* voteAcc  = (float*)((char*)bar + 64);
  u16* vhb        = (u16*)wsAlloc((size_t)2 * SLOT * 2);               // 4 MB
  u64* Abits      = (u64*)wsAlloc((size_t)Bk * Nk * 32 * 8);           // 4 MB
  u64* diagBits   = (u64*)wsAlloc((size_t)Bk * 32 * 8);                // 2 KB
  float* partial  = (float*)wsAlloc((size_t)2 * GBLK * 64 * 4);        // 128 KB
  u16* wcat       = (u16*)wsAlloc(256 * 128 * 2);
  u16* cwcat      = (u16*)wsAlloc(256 * 128 * 2);
  u16* vw1        = (u16*)wsAlloc(112 * 64 * 2);
  u16* vw2        = (u16*)wsAlloc(64 * 128 * 2);
  u16* cw1        = (u16*)wsAlloc(112 * 64 * 2);
  u16* cw2        = (u16*)wsAlloc(64 * 128 * 2);

  k_init_w<<<1, 256, 0, stream>>>(vWih, vWhh, cWih, cWhh, vm1, vm2, cm1, cm2,
                                  wcat, cwcat, vw1, vw2, cw1, cw2, bar, voteAcc, diagBits);
  k_init_vt<<<256, 256, 0, stream>>>(vInit, vhb);
  k_bits<<<Bk * Nk / 4, 256, 0, stream>>>(Mvv, Abits, diagBits);

  (void)hipFuncSetAttribute((const void*)k_persist,
                            hipFuncAttributeMaxDynamicSharedMemorySize, LDS_TOTAL);
  PArgs pa;
  pa.vWih = vWih; pa.chInit = chInit;
  pa.vbih = vbih; pa.vbhh = vbhh; pa.cbih = cbih; pa.cbhh = cbhh;
  pa.vmb1 = vmb1; pa.vmb2 = vmb2; pa.cmb1 = cmb1; pa.cmb2 = cmb2;
  pa.voW1 = voW1; pa.vob1 = vob1; pa.voW2 = voW2; pa.vob2 = vob2;
  pa.ncolors = ncol;
  pa.vhbuf = vhb; pa.Abits = Abits; pa.diagBits = diagBits; pa.partial = partial;
  pa.wcat = wcat; pa.cwcat = cwcat; pa.vw1 = vw1; pa.vw2 = vw2; pa.cw1 = cw1; pa.cw2 = cw2;
  pa.bar = bar; pa.voteAcc = voteAcc; pa.out = (float*)d_out;
  k_persist<<<GBLK, 256, LDS_TOTAL, stream>>>(pa);
}